// Round 2
// baseline (4025.238 us; speedup 1.0000x reference)
//
#include <hip/hip_runtime.h>
#include <hip/hip_bf16.h>
#include <math.h>

typedef __attribute__((ext_vector_type(4))) float f32x4;
typedef __attribute__((ext_vector_type(8))) short bf16x8;
typedef __attribute__((ext_vector_type(4))) short bf16x4;

static __device__ __forceinline__ float bf2f(short u){
  unsigned int i = ((unsigned int)(unsigned short)u) << 16;
  return __builtin_bit_cast(float, i);
}
static __device__ __forceinline__ short f2bf(float f){
  unsigned int u = __builtin_bit_cast(unsigned int, f);
  u += 0x7FFFu + ((u >> 16) & 1u);   // RNE
  return (short)(u >> 16);
}

// ---------------------------------------------------------------------------
// Generic C[M,N] = A[M,K] @ B[K,N].  A: f32 or bf16 row-major; B: f32 row-major;
// C: f32 or bf16.  128x128 tile, BK=32, 256 threads (4 waves, 2x2), MFMA 16x16x32.
// LDS layout: As[row][k], Bs[col][k], both bf16 with XOR-granule swizzle.
// ---------------------------------------------------------------------------
template<typename AT, typename CT>
__global__ __launch_bounds__(256) void mla_gemm(const AT* __restrict__ A,
                                                const float* __restrict__ B,
                                                CT* __restrict__ C,
                                                int M, int N, int K)
{
  __shared__ __align__(16) short As[128*32];
  __shared__ __align__(16) short Bs[128*32];
  const int tid = threadIdx.x;
  const int m0 = blockIdx.x * 128, n0 = blockIdx.y * 128;
  const int w = tid >> 6, lane = tid & 63;
  const int wr = w >> 1, wc = w & 1;
  const int g = lane >> 4, l16 = lane & 15;
  char* AsB = (char*)As; char* BsB = (char*)Bs;

  f32x4 acc[4][4];
  #pragma unroll
  for (int i=0;i<4;i++)
    #pragma unroll
    for (int j=0;j<4;j++) acc[i][j] = (f32x4){0.f,0.f,0.f,0.f};

  for (int k0 = 0; k0 < K; k0 += 32) {
    __syncthreads();
    // ---- stage A tile: 128 rows x 32 k ----
    if constexpr (sizeof(AT) == 4) {
      #pragma unroll
      for (int c=0;c<4;c++){
        int lin = c*256 + tid;                 // 1024 chunks of 4 f32
        int row = lin >> 3, kc = (lin & 7) << 2;
        const f32x4 av = *reinterpret_cast<const f32x4*>(A + (size_t)(m0+row)*K + k0 + kc);
        bf16x4 h; h[0]=f2bf(av[0]); h[1]=f2bf(av[1]); h[2]=f2bf(av[2]); h[3]=f2bf(av[3]);
        unsigned byte = (unsigned)(row*64 + kc*2) ^ ((unsigned)(row&7)<<4);
        *reinterpret_cast<bf16x4*>(AsB + byte) = h;
      }
    } else {
      #pragma unroll
      for (int c=0;c<2;c++){
        int lin = c*256 + tid;                 // 512 chunks of 8 bf16
        int row = lin >> 2, kc = (lin & 3) << 3;   // 128 rows x 4 chunks  (FIXED)
        bf16x8 av = *reinterpret_cast<const bf16x8*>(A + (size_t)(m0+row)*K + k0 + kc);
        unsigned byte = (unsigned)(row*64 + kc*2) ^ ((unsigned)(row&7)<<4);
        *reinterpret_cast<bf16x8*>(AsB + byte) = av;
      }
    }
    // ---- stage B tile: 32 k x 128 n -> Bs[col][k] (transposed scatter) ----
    #pragma unroll
    for (int c=0;c<4;c++){
      int lin = c*256 + tid;                   // 1024 chunks of 4 f32
      int k = lin >> 5, nc = (lin & 31) << 2;
      f32x4 bv = (f32x4){0.f,0.f,0.f,0.f};
      if (n0 + nc < N)                          // N is a multiple of 16: chunk all-in or all-out
        bv = *reinterpret_cast<const f32x4*>(B + (size_t)(k0+k)*N + n0 + nc);
      #pragma unroll
      for (int i=0;i<4;i++){
        unsigned byte = (unsigned)((nc+i)*64 + k*2) ^ ((unsigned)((nc+i)&7)<<4);
        *reinterpret_cast<short*>(BsB + byte) = f2bf(bv[i]);
      }
    }
    __syncthreads();
    // ---- fragments + MFMA ----
    bf16x8 af[4], bfm[4];
    #pragma unroll
    for (int mi=0;mi<4;mi++){
      int row = wr*64 + mi*16 + l16;
      unsigned byte = ((unsigned)(row*64 + g*16)) ^ ((unsigned)(row&7)<<4);
      af[mi] = *reinterpret_cast<const bf16x8*>(AsB + byte);
    }
    #pragma unroll
    for (int ni=0;ni<4;ni++){
      int col = wc*64 + ni*16 + l16;
      unsigned byte = ((unsigned)(col*64 + g*16)) ^ ((unsigned)(col&7)<<4);
      bfm[ni] = *reinterpret_cast<const bf16x8*>(BsB + byte);
    }
    #pragma unroll
    for (int mi=0;mi<4;mi++)
      #pragma unroll
      for (int ni=0;ni<4;ni++)
        acc[mi][ni] = __builtin_amdgcn_mfma_f32_16x16x32_bf16(af[mi], bfm[ni], acc[mi][ni], 0, 0, 0);
  }

  // ---- epilogue: C/D layout col=lane&15, row=(lane>>4)*4+r ----
  #pragma unroll
  for (int mi=0;mi<4;mi++){
    int row = m0 + wr*64 + mi*16 + g*4;
    #pragma unroll
    for (int ni=0;ni<4;ni++){
      int col = n0 + wc*64 + ni*16 + l16;
      if (col < N){
        #pragma unroll
        for (int r=0;r<4;r++){
          if constexpr (sizeof(CT) == 4)
            C[(size_t)(row+r)*N + col] = acc[mi][ni][r];
          else
            C[(size_t)(row+r)*N + col] = f2bf(acc[mi][ni][r]);
        }
      }
    }
  }
}

// ---------------------------------------------------------------------------
// In-place row RMS norm (f32): x = x * rsqrt(mean(x^2)+eps) * scale
// ---------------------------------------------------------------------------
__global__ __launch_bounds__(256) void mla_rmsnorm(float* __restrict__ x,
                                                   const float* __restrict__ scale, int ncols)
{
  const int t = blockIdx.x;
  float* row = x + (size_t)t * ncols;
  float ss = 0.f;
  for (int i = threadIdx.x; i < ncols; i += 256){ float v = row[i]; ss += v*v; }
  #pragma unroll
  for (int off = 32; off >= 1; off >>= 1) ss += __shfl_xor(ss, off);
  __shared__ float red[4];
  if ((threadIdx.x & 63) == 0) red[threadIdx.x >> 6] = ss;
  __syncthreads();
  ss = red[0] + red[1] + red[2] + red[3];
  const float rs = 1.0f / sqrtf(ss / (float)ncols + 1e-6f);
  for (int i = threadIdx.x; i < ncols; i += 256) row[i] = row[i] * rs * scale[i];
}

// ---------------------------------------------------------------------------
// YaRN (DeepseekScalingRotaryEmbedding) cos/sin, double precision internals
// ---------------------------------------------------------------------------
__device__ __forceinline__ void yarn_cs(int pos, int j, float& c, float& s){
  const double dim = 64.0;
  double pf = pow(10000.0, (2.0*(double)j)/dim);
  double inv_extra = 1.0/pf;
  double inv_inter = inv_extra/40.0;
  double lo = floor(dim*log(4096.0/(32.0*2.0*M_PI))/(2.0*log(10000.0)));
  double hi = ceil (dim*log(4096.0/(       2.0*M_PI))/(2.0*log(10000.0)));
  if (lo < 0.0) lo = 0.0;
  if (hi > dim - 1.0) hi = dim - 1.0;
  double denom = hi - lo; if (denom < 0.001) denom = 0.001;
  double ramp = ((double)j - lo)/denom;
  ramp = ramp < 0.0 ? 0.0 : (ramp > 1.0 ? 1.0 : ramp);
  double mask = 1.0 - ramp;
  float invf = (float)(inv_inter*(1.0 - mask) + inv_extra*mask);
  float ang = (float)pos * invf;
  c = cosf(ang); s = sinf(ang);
}

// ---------------------------------------------------------------------------
// In-place RoPE on q (cols 128..191 of each 192 group) + fold 192^-0.5 * 1/16
// q_b: bf16 [T, N*192]
// ---------------------------------------------------------------------------
__global__ __launch_bounds__(256) void mla_rope_q(short* __restrict__ qb,
                                                  const int* __restrict__ positions)
{
  const int t = blockIdx.x;
  __shared__ float cs[32], sn[32];
  if (threadIdx.x < 32){
    float c, s; yarn_cs(positions[t], threadIdx.x, c, s);
    cs[threadIdx.x] = c; sn[threadIdx.x] = s;
  }
  __syncthreads();
  const float f = 0.004510548978043951f;   // 192^-0.5 * 256^-0.5 (qk scale * sm_scale)
  short* row = qb + (size_t)t * 24576;
  for (int idx = threadIdx.x; idx < 128*160; idx += 256){
    int n = idx / 160, e = idx % 160;
    short* p = row + n*192;
    if (e < 128){
      p[e] = f2bf(bf2f(p[e]) * f);
    } else {
      int j = e - 128;
      float x1 = bf2f(p[128+j]), x2 = bf2f(p[160+j]);
      p[128+j] = f2bf((x1*cs[j] - x2*sn[j]) * f);
      p[160+j] = f2bf((x2*cs[j] + x1*sn[j]) * f);
    }
  }
}

// ---------------------------------------------------------------------------
// kv_SA [T,576] f32 -> c [T,512] f32 (rmsnorm*scale), krope [T,64] bf16 (rope)
// ---------------------------------------------------------------------------
__global__ __launch_bounds__(256) void mla_kv_post(const float* __restrict__ kv,
                                                   const float* __restrict__ scale,
                                                   const int* __restrict__ positions,
                                                   float* __restrict__ cbuf,
                                                   short* __restrict__ krope)
{
  const int t = blockIdx.x;
  const float* row = kv + (size_t)t * 576;
  float ss = 0.f;
  for (int i = threadIdx.x; i < 512; i += 256){ float v = row[i]; ss += v*v; }
  #pragma unroll
  for (int off = 32; off >= 1; off >>= 1) ss += __shfl_xor(ss, off);
  __shared__ float red[4];
  if ((threadIdx.x & 63) == 0) red[threadIdx.x >> 6] = ss;
  __syncthreads();
  ss = red[0] + red[1] + red[2] + red[3];
  const float rs = 1.0f / sqrtf(ss / 512.f + 1e-6f);
  for (int i = threadIdx.x; i < 512; i += 256)
    cbuf[(size_t)t*512 + i] = row[i] * rs * scale[i];
  if (threadIdx.x < 32){
    int j = threadIdx.x;
    float c, s; yarn_cs(positions[t], j, c, s);
    float x1 = row[512 + j], x2 = row[544 + j];
    krope[(size_t)t*64 + j]      = f2bf(x1*c - x2*s);
    krope[(size_t)t*64 + 32 + j] = f2bf(x2*c + x1*s);
  }
}

// ---------------------------------------------------------------------------
// Flash attention, causal. Block = (q-tile of 64 rows) x (1 head).
// 4 waves x 16 q-rows. QBLK=SBLK=64. Scales pre-folded into q.
// q_b   bf16 [T, N*192]
// kvup  bf16 [T, N*256]  (cols n*256+0..127 = k_nope, 128..255 = v)
// krope bf16 [T, 64]     (shared across heads)
// out   bf16 [T, N*128]
// ---------------------------------------------------------------------------
__global__ __launch_bounds__(256) void mla_attn(const short* __restrict__ qb,
                                                const short* __restrict__ kvup,
                                                const short* __restrict__ krope,
                                                short* __restrict__ attn_out)
{
  const int qt = blockIdx.x;        // 0..15
  const int n  = blockIdx.y;        // head
  const int tid = threadIdx.x, w = tid >> 6, lane = tid & 63;
  const int g = lane >> 4, l16 = lane & 15;
  const int t0 = qt * 64;

  __shared__ __align__(16) short Klds[64*192];    // [s][h], row 384B, swizzled
  __shared__ __align__(16) short Vlds[128*64];    // V^T [v][s], row 128B, swizzled
  __shared__ __align__(16) short Plds[4][16*64];  // per-wave P [q][s], row 128B, swizzled
  char* KB = (char*)Klds; char* VB = (char*)Vlds; char* PB = (char*)Plds[w];

  // Q fragments (A-operand), rows t0 + w*16 + l16, k = c*32 + g*8 + b
  bf16x8 qf[6];
  {
    const size_t qrow = (size_t)(t0 + w*16 + l16) * 24576 + (size_t)n * 192;
    #pragma unroll
    for (int c=0;c<6;c++)
      qf[c] = *reinterpret_cast<const bf16x8*>(qb + qrow + c*32 + g*8);
  }

  f32x4 o[8];
  #pragma unroll
  for (int i=0;i<8;i++) o[i] = (f32x4){0.f,0.f,0.f,0.f};
  float m[4], l[4];
  #pragma unroll
  for (int r=0;r<4;r++){ m[r] = -1e30f; l[r] = 0.f; }

  for (int sb = 0; sb <= qt; sb++){
    __syncthreads();
    // stage K tile: 64 s x 192 h (nope from kvup, rope from krope)
    #pragma unroll
    for (int c=0;c<6;c++){
      int lin = c*256 + tid;
      int s = lin / 24, hb = (lin % 24) * 8;
      bf16x8 kv;
      if (hb < 128) kv = *reinterpret_cast<const bf16x8*>(kvup + (size_t)(sb*64+s)*32768 + n*256 + hb);
      else          kv = *reinterpret_cast<const bf16x8*>(krope + (size_t)(sb*64+s)*64 + (hb-128));
      unsigned byte = (unsigned)(s*384 + hb*2) ^ ((unsigned)(s&7)<<4);
      *reinterpret_cast<bf16x8*>(KB + byte) = kv;
    }
    // stage V^T: 64 s x 128 v -> Vlds[v][s]
    #pragma unroll
    for (int c=0;c<4;c++){
      int lin = c*256 + tid;
      int s = lin >> 4, vb = (lin & 15) << 3;
      bf16x8 vv = *reinterpret_cast<const bf16x8*>(kvup + (size_t)(sb*64+s)*32768 + n*256 + 128 + vb);
      #pragma unroll
      for (int i=0;i<8;i++){
        unsigned byte = (unsigned)((vb+i)*128 + s*2) ^ ((unsigned)((vb+i)&7)<<4);
        *reinterpret_cast<short*>(VB + byte) = vv[i];
      }
    }
    __syncthreads();

    // S = Q K^T : 4 s-tiles of 16, each 6 MFMAs over h
    f32x4 S[4];
    #pragma unroll
    for (int st=0; st<4; st++){
      f32x4 sacc = (f32x4){0.f,0.f,0.f,0.f};
      int srow = st*16 + l16;
      #pragma unroll
      for (int c=0;c<6;c++){
        unsigned byte = (unsigned)(srow*384 + c*64 + g*16) ^ ((unsigned)(srow&7)<<4);
        bf16x8 kf = *reinterpret_cast<const bf16x8*>(KB + byte);
        sacc = __builtin_amdgcn_mfma_f32_16x16x32_bf16(qf[c], kf, sacc, 0, 0, 0);
      }
      S[st] = sacc;
    }
    // causal mask on the diagonal block
    if (sb == qt){
      #pragma unroll
      for (int st=0;st<4;st++){
        int scol = st*16 + l16;
        #pragma unroll
        for (int r=0;r<4;r++){
          int qrow = w*16 + g*4 + r;
          if (scol > qrow) S[st][r] = -1e30f;
        }
      }
    }
    // online softmax
    float alpha[4];
    #pragma unroll
    for (int r=0;r<4;r++){
      float mx = fmaxf(fmaxf(S[0][r],S[1][r]), fmaxf(S[2][r],S[3][r]));
      #pragma unroll
      for (int off=8; off>=1; off>>=1) mx = fmaxf(mx, __shfl_xor(mx, off));
      float mnew = fmaxf(m[r], mx);
      alpha[r] = expf(m[r] - mnew);
      m[r] = mnew;
      l[r] *= alpha[r];
    }
    #pragma unroll
    for (int st=0;st<4;st++)
      #pragma unroll
      for (int r=0;r<4;r++)
        S[st][r] = expf(S[st][r] - m[r]);
    #pragma unroll
    for (int r=0;r<4;r++){
      float sum = S[0][r]+S[1][r]+S[2][r]+S[3][r];
      #pragma unroll
      for (int off=8; off>=1; off>>=1) sum += __shfl_xor(sum, off);
      l[r] += sum;
    }
    #pragma unroll
    for (int vt=0; vt<8; vt++)
      #pragma unroll
      for (int r=0;r<4;r++) o[vt][r] *= alpha[r];

    // P -> per-wave LDS (bf16), then PV MFMAs
    #pragma unroll
    for (int st=0;st<4;st++){
      #pragma unroll
      for (int r=0;r<4;r++){
        int qrow = g*4 + r, scol = st*16 + l16;
        unsigned byte = (unsigned)(qrow*128 + scol*2) ^ ((unsigned)(qrow&7)<<4);
        *reinterpret_cast<short*>(PB + byte) = f2bf(S[st][r]);
      }
    }
    bf16x8 pf[2];
    #pragma unroll
    for (int c=0;c<2;c++){
      unsigned byte = (unsigned)(l16*128 + (c*32 + g*8)*2) ^ ((unsigned)(l16&7)<<4);
      pf[c] = *reinterpret_cast<const bf16x8*>(PB + byte);
    }
    #pragma unroll
    for (int vt=0; vt<8; vt++){
      #pragma unroll
      for (int c=0;c<2;c++){
        int vrow = vt*16 + l16;
        unsigned byte = (unsigned)(vrow*128 + (c*32 + g*8)*2) ^ ((unsigned)(vrow&7)<<4);
        bf16x8 vf = *reinterpret_cast<const bf16x8*>(VB + byte);
        o[vt] = __builtin_amdgcn_mfma_f32_16x16x32_bf16(pf[c], vf, o[vt], 0, 0, 0);
      }
    }
  }

  // epilogue: divide by l, store bf16
  #pragma unroll
  for (int r=0;r<4;r++){
    float inv = 1.f / l[r];
    int t = t0 + w*16 + g*4 + r;
    #pragma unroll
    for (int vt=0;vt<8;vt++){
      int v = vt*16 + l16;
      attn_out[(size_t)t*16384 + n*128 + v] = f2bf(o[vt][r] * inv);
    }
  }
}

// ---------------------------------------------------------------------------
extern "C" void kernel_launch(void* const* d_in, const int* in_sizes, int n_in,
                              void* d_out, int out_size, void* d_ws, size_t ws_size,
                              hipStream_t stream) {
  const float* x            = (const float*)d_in[0];
  const int*   positions    = (const int*)  d_in[1];
  const float* w_q_down     = (const float*)d_in[2];
  const float* q_norm_scale = (const float*)d_in[3];
  const float* w_q_up       = (const float*)d_in[4];
  const float* w_kv_down    = (const float*)d_in[5];
  const float* kv_norm_scale= (const float*)d_in[6];
  const float* w_kv_up      = (const float*)d_in[7];
  const float* w_o          = (const float*)d_in[8];

  char* p = (char*)d_ws;
  float* q_TA   = (float*)p; p += (size_t)1024*1536*4;   // 6.3 MB
  short* q_b    = (short*)p; p += (size_t)1024*24576*2;  // 50.3 MB
  float* kv_SA  = (float*)p; p += (size_t)1024*576*4;    // 2.4 MB
  float* cbuf   = (float*)p; p += (size_t)1024*512*4;    // 2.1 MB
  short* krope  = (short*)p; p += (size_t)1024*64*2;     // 0.13 MB
  short* kvup   = (short*)p; p += (size_t)1024*32768*2;  // 67 MB
  short* attn_o = (short*)p; p += (size_t)1024*16384*2;  // 33.6 MB

  dim3 blk(256);
  // q path
  mla_gemm<float, float><<<dim3(8, 12), blk, 0, stream>>>(x, w_q_down, q_TA, 1024, 1536, 7168);
  mla_rmsnorm<<<1024, blk, 0, stream>>>(q_TA, q_norm_scale, 1536);
  mla_gemm<float, short><<<dim3(8, 192), blk, 0, stream>>>(q_TA, w_q_up, q_b, 1024, 24576, 1536);
  mla_rope_q<<<1024, blk, 0, stream>>>(q_b, positions);
  // kv path
  mla_gemm<float, float><<<dim3(8, 5), blk, 0, stream>>>(x, w_kv_down, kv_SA, 1024, 576, 7168);
  mla_kv_post<<<1024, blk, 0, stream>>>(kv_SA, kv_norm_scale, positions, cbuf, krope);
  mla_gemm<float, short><<<dim3(8, 256), blk, 0, stream>>>(cbuf, w_kv_up, kvup, 1024, 32768, 512);
  // attention
  mla_attn<<<dim3(16, 128), blk, 0, stream>>>(q_b, kvup, krope, attn_o);
  // output projection
  mla_gemm<short, float><<<dim3(8, 56), blk, 0, stream>>>(attn_o, w_o, (float*)d_out, 1024, 7168, 16384);
}

// Round 3
// 1898.357 us; speedup vs baseline: 2.1204x; 2.1204x over previous
//
#include <hip/hip_runtime.h>
#include <hip/hip_bf16.h>
#include <math.h>

typedef __attribute__((ext_vector_type(4))) float f32x4;
typedef __attribute__((ext_vector_type(8))) short bf16x8;
typedef __attribute__((ext_vector_type(4))) short bf16x4;

static __device__ __forceinline__ float bf2f(short u){
  unsigned int i = ((unsigned int)(unsigned short)u) << 16;
  return __builtin_bit_cast(float, i);
}
static __device__ __forceinline__ short f2bf(float f){
  unsigned int u = __builtin_bit_cast(unsigned int, f);
  u += 0x7FFFu + ((u >> 16) & 1u);   // RNE
  return (short)(u >> 16);
}

#define GLD16(g, l) __builtin_amdgcn_global_load_lds(                         \
    (const __attribute__((address_space(1))) void*)(g),                       \
    (__attribute__((address_space(3))) void*)(l), 16, 0, 0)

// ---------------------------------------------------------------------------
// C[M,N] = A[M,K] @ BT[N,K]^T.  A,BT bf16 row-major. C f32 or bf16.
// m97 structure: 128x128 tile, BK=32, 256 thr (4 waves 2x2), linear LDS,
// global_load_lds dwordx4 staging, 16 MFMA + 8 ds_read_b128 per K-step.
// ---------------------------------------------------------------------------
template<typename CT>
__global__ __launch_bounds__(256) void gemm_bt(const short* __restrict__ A,
                                               const short* __restrict__ BT,
                                               CT* __restrict__ C,
                                               int M, int N, int K)
{
  __shared__ __align__(16) short As[128*32];
  __shared__ __align__(16) short Bs[128*32];
  const int tid = threadIdx.x;
  const int m0 = blockIdx.x * 128, n0 = blockIdx.y * 128;
  const int w = tid >> 6, lane = tid & 63;
  const int wr = w >> 1, wc = w & 1;
  const int g = lane >> 4, l16 = lane & 15;

  // staging: 8 chunks of 1KB per tile; wave w handles chunks {w, w+4}.
  // chunk c covers rows c*16..c*16+15 (64B of bf16 k per row).
  const int sr = lane >> 2;           // row within chunk
  const int kc = (lane & 3) << 3;     // k offset (shorts)
  const int arow0 = m0 + w*16 + sr;
  const int arow1 = m0 + (w+4)*16 + sr;
  int brow0 = n0 + w*16 + sr;      if (brow0 >= N) brow0 = N - 1;
  int brow1 = n0 + (w+4)*16 + sr;  if (brow1 >= N) brow1 = N - 1;
  const short* aG0 = A  + (size_t)arow0 * K + kc;
  const short* aG1 = A  + (size_t)arow1 * K + kc;
  const short* bG0 = BT + (size_t)brow0 * K + kc;
  const short* bG1 = BT + (size_t)brow1 * K + kc;
  char* aL0 = (char*)As + (w  )*1024;
  char* aL1 = (char*)As + (w+4)*1024;
  char* bL0 = (char*)Bs + (w  )*1024;
  char* bL1 = (char*)Bs + (w+4)*1024;

  f32x4 acc[4][4];
  #pragma unroll
  for (int i=0;i<4;i++)
    #pragma unroll
    for (int j=0;j<4;j++) acc[i][j] = (f32x4){0.f,0.f,0.f,0.f};

  for (int k0 = 0; k0 < K; k0 += 32){
    __syncthreads();
    GLD16(aG0 + k0, aL0);
    GLD16(aG1 + k0, aL1);
    GLD16(bG0 + k0, bL0);
    GLD16(bG1 + k0, bL1);
    __syncthreads();

    bf16x8 af[4], bfm[4];
    #pragma unroll
    for (int mi=0;mi<4;mi++){
      int row = wr*64 + mi*16 + l16;
      af[mi] = *reinterpret_cast<const bf16x8*>((char*)As + row*64 + g*16);
    }
    #pragma unroll
    for (int ni=0;ni<4;ni++){
      int row = wc*64 + ni*16 + l16;
      bfm[ni] = *reinterpret_cast<const bf16x8*>((char*)Bs + row*64 + g*16);
    }
    #pragma unroll
    for (int mi=0;mi<4;mi++)
      #pragma unroll
      for (int ni=0;ni<4;ni++)
        acc[mi][ni] = __builtin_amdgcn_mfma_f32_16x16x32_bf16(af[mi], bfm[ni], acc[mi][ni], 0, 0, 0);
  }

  // epilogue: C/D layout col=lane&15, row=(lane>>4)*4+r
  #pragma unroll
  for (int mi=0;mi<4;mi++){
    int row = m0 + wr*64 + mi*16 + g*4;
    #pragma unroll
    for (int ni=0;ni<4;ni++){
      int col = n0 + wc*64 + ni*16 + l16;
      if (col < N){
        #pragma unroll
        for (int r=0;r<4;r++){
          if constexpr (sizeof(CT) == 4)
            C[(size_t)(row+r)*N + col] = acc[mi][ni][r];
          else
            C[(size_t)(row+r)*N + col] = f2bf(acc[mi][ni][r]);
        }
      }
    }
  }
}

// ---------------------------------------------------------------------------
// dst[C][R] (bf16) = transpose(src[R][C] (f32)).  R,C multiples of 64.
// 64x64 tile via LDS f32 [64][68] (4-way max on read side).
// ---------------------------------------------------------------------------
__global__ __launch_bounds__(256) void transpose_f32_bf16(const float* __restrict__ src,
                                                          short* __restrict__ dst,
                                                          int R, int C)
{
  __shared__ float tl[64][68];
  const int tid = threadIdx.x;
  const int r0 = blockIdx.y * 64, c0 = blockIdx.x * 64;
  {
    const int lr = tid >> 4, lc = (tid & 15) << 2;
    #pragma unroll
    for (int p = 0; p < 4; p++){
      int row = p*16 + lr;
      f32x4 v = *reinterpret_cast<const f32x4*>(src + (size_t)(r0+row)*C + c0 + lc);
      *reinterpret_cast<f32x4*>(&tl[row][lc]) = v;
    }
  }
  __syncthreads();
  {
    const int n = tid >> 2, ks = (tid & 3) << 4;
    short tmp[16];
    #pragma unroll
    for (int j = 0; j < 16; j++) tmp[j] = f2bf(tl[ks + j][n]);
    short* d = dst + (size_t)(c0+n)*R + r0 + ks;
    *reinterpret_cast<bf16x8*>(d)     = *reinterpret_cast<bf16x8*>(&tmp[0]);
    *reinterpret_cast<bf16x8*>(d + 8) = *reinterpret_cast<bf16x8*>(&tmp[8]);
  }
}

// ---------------------------------------------------------------------------
// f32 -> bf16 elementwise (n4 = count/4)
// ---------------------------------------------------------------------------
__global__ __launch_bounds__(256) void conv_f32_bf16(const float* __restrict__ src,
                                                     short* __restrict__ dst, int n4)
{
  int i = blockIdx.x * 256 + threadIdx.x;
  const int stride = gridDim.x * 256;
  for (; i < n4; i += stride){
    f32x4 v = reinterpret_cast<const f32x4*>(src)[i];
    bf16x4 h; h[0]=f2bf(v[0]); h[1]=f2bf(v[1]); h[2]=f2bf(v[2]); h[3]=f2bf(v[3]);
    reinterpret_cast<bf16x4*>(dst)[i] = h;
  }
}

// ---------------------------------------------------------------------------
// RMS norm over cols [0,1536) of downC [1024][2112] f32 -> bf16 out [1024][1536]
// ---------------------------------------------------------------------------
__global__ __launch_bounds__(256) void mla_rmsnorm_bf(const float* __restrict__ dc,
                                                      const float* __restrict__ scale,
                                                      short* __restrict__ out)
{
  const int t = blockIdx.x;
  const float* row = dc + (size_t)t * 2112;
  float ss = 0.f;
  for (int i = threadIdx.x; i < 1536; i += 256){ float v = row[i]; ss += v*v; }
  #pragma unroll
  for (int off = 32; off >= 1; off >>= 1) ss += __shfl_xor(ss, off);
  __shared__ float red[4];
  if ((threadIdx.x & 63) == 0) red[threadIdx.x >> 6] = ss;
  __syncthreads();
  ss = red[0] + red[1] + red[2] + red[3];
  const float rs = 1.0f / sqrtf(ss / 1536.f + 1e-6f);
  for (int i = threadIdx.x; i < 1536; i += 256)
    out[(size_t)t*1536 + i] = f2bf(row[i] * rs * scale[i]);
}

// ---------------------------------------------------------------------------
// YaRN cos/sin (double internals, matches reference constants)
// ---------------------------------------------------------------------------
__device__ __forceinline__ void yarn_cs(int pos, int j, float& c, float& s){
  const double dim = 64.0;
  double pf = pow(10000.0, (2.0*(double)j)/dim);
  double inv_extra = 1.0/pf;
  double inv_inter = inv_extra/40.0;
  double lo = floor(dim*log(4096.0/(32.0*2.0*M_PI))/(2.0*log(10000.0)));
  double hi = ceil (dim*log(4096.0/(       2.0*M_PI))/(2.0*log(10000.0)));
  if (lo < 0.0) lo = 0.0;
  if (hi > dim - 1.0) hi = dim - 1.0;
  double denom = hi - lo; if (denom < 0.001) denom = 0.001;
  double ramp = ((double)j - lo)/denom;
  ramp = ramp < 0.0 ? 0.0 : (ramp > 1.0 ? 1.0 : ramp);
  double mask = 1.0 - ramp;
  float invf = (float)(inv_inter*(1.0 - mask) + inv_extra*mask);
  float ang = (float)pos * invf;
  c = cosf(ang); s = sinf(ang);
}

// ---------------------------------------------------------------------------
// In-place RoPE on q (cols 128..191 of each 192 group) + fold 192^-.5 * 256^-.5
// ---------------------------------------------------------------------------
__global__ __launch_bounds__(256) void mla_rope_q(short* __restrict__ qb,
                                                  const int* __restrict__ positions)
{
  const int t = blockIdx.x;
  __shared__ float cs[32], sn[32];
  if (threadIdx.x < 32){
    float c, s; yarn_cs(positions[t], threadIdx.x, c, s);
    cs[threadIdx.x] = c; sn[threadIdx.x] = s;
  }
  __syncthreads();
  const float f = 0.004510548978043951f;   // 192^-0.5 * 256^-0.5
  short* row = qb + (size_t)t * 24576;
  for (int idx = threadIdx.x; idx < 128*160; idx += 256){
    int n = idx / 160, e = idx % 160;
    short* p = row + n*192;
    if (e < 128){
      p[e] = f2bf(bf2f(p[e]) * f);
    } else {
      int j = e - 128;
      float x1 = bf2f(p[128+j]), x2 = bf2f(p[160+j]);
      p[128+j] = f2bf((x1*cs[j] - x2*sn[j]) * f);
      p[160+j] = f2bf((x2*cs[j] + x1*sn[j]) * f);
    }
  }
}

// ---------------------------------------------------------------------------
// downC cols [1536,2112) -> cbuf bf16 [1024][512] (rmsnorm), krope bf16 (rope)
// ---------------------------------------------------------------------------
__global__ __launch_bounds__(256) void mla_kv_post(const float* __restrict__ dc,
                                                   const float* __restrict__ scale,
                                                   const int* __restrict__ positions,
                                                   short* __restrict__ cbuf,
                                                   short* __restrict__ krope)
{
  const int t = blockIdx.x;
  const float* row = dc + (size_t)t * 2112 + 1536;
  float ss = 0.f;
  for (int i = threadIdx.x; i < 512; i += 256){ float v = row[i]; ss += v*v; }
  #pragma unroll
  for (int off = 32; off >= 1; off >>= 1) ss += __shfl_xor(ss, off);
  __shared__ float red[4];
  if ((threadIdx.x & 63) == 0) red[threadIdx.x >> 6] = ss;
  __syncthreads();
  ss = red[0] + red[1] + red[2] + red[3];
  const float rs = 1.0f / sqrtf(ss / 512.f + 1e-6f);
  for (int i = threadIdx.x; i < 512; i += 256)
    cbuf[(size_t)t*512 + i] = f2bf(row[i] * rs * scale[i]);
  if (threadIdx.x < 32){
    int j = threadIdx.x;
    float c, s; yarn_cs(positions[t], j, c, s);
    float x1 = row[512 + j], x2 = row[544 + j];
    krope[(size_t)t*64 + j]      = f2bf(x1*c - x2*s);
    krope[(size_t)t*64 + 32 + j] = f2bf(x2*c + x1*s);
  }
}

// ---------------------------------------------------------------------------
// Flash attention, causal. Block = (64 q-rows) x (1 head). 4 waves.
// ---------------------------------------------------------------------------
__global__ __launch_bounds__(256) void mla_attn(const short* __restrict__ qb,
                                                const short* __restrict__ kvup,
                                                const short* __restrict__ krope,
                                                short* __restrict__ attn_out)
{
  const int qt = blockIdx.x;        // 0..15
  const int n  = blockIdx.y;        // head
  const int tid = threadIdx.x, w = tid >> 6, lane = tid & 63;
  const int g = lane >> 4, l16 = lane & 15;
  const int t0 = qt * 64;

  __shared__ __align__(16) short Klds[64*192];
  __shared__ __align__(16) short Vlds[128*64];
  __shared__ __align__(16) short Plds[4][16*64];
  char* KB = (char*)Klds; char* VB = (char*)Vlds; char* PB = (char*)Plds[w];

  bf16x8 qf[6];
  {
    const size_t qrow = (size_t)(t0 + w*16 + l16) * 24576 + (size_t)n * 192;
    #pragma unroll
    for (int c=0;c<6;c++)
      qf[c] = *reinterpret_cast<const bf16x8*>(qb + qrow + c*32 + g*8);
  }

  f32x4 o[8];
  #pragma unroll
  for (int i=0;i<8;i++) o[i] = (f32x4){0.f,0.f,0.f,0.f};
  float m[4], l[4];
  #pragma unroll
  for (int r=0;r<4;r++){ m[r] = -1e30f; l[r] = 0.f; }

  for (int sb = 0; sb <= qt; sb++){
    __syncthreads();
    #pragma unroll
    for (int c=0;c<6;c++){
      int lin = c*256 + tid;
      int s = lin / 24, hb = (lin % 24) * 8;
      bf16x8 kv;
      if (hb < 128) kv = *reinterpret_cast<const bf16x8*>(kvup + (size_t)(sb*64+s)*32768 + n*256 + hb);
      else          kv = *reinterpret_cast<const bf16x8*>(krope + (size_t)(sb*64+s)*64 + (hb-128));
      unsigned byte = (unsigned)(s*384 + hb*2) ^ ((unsigned)(s&7)<<4);
      *reinterpret_cast<bf16x8*>(KB + byte) = kv;
    }
    #pragma unroll
    for (int c=0;c<4;c++){
      int lin = c*256 + tid;
      int s = lin >> 4, vb = (lin & 15) << 3;
      bf16x8 vv = *reinterpret_cast<const bf16x8*>(kvup + (size_t)(sb*64+s)*32768 + n*256 + 128 + vb);
      #pragma unroll
      for (int i=0;i<8;i++){
        unsigned byte = (unsigned)((vb+i)*128 + s*2) ^ ((unsigned)((vb+i)&7)<<4);
        *reinterpret_cast<short*>(VB + byte) = vv[i];
      }
    }
    __syncthreads();

    f32x4 S[4];
    #pragma unroll
    for (int st=0; st<4; st++){
      f32x4 sacc = (f32x4){0.f,0.f,0.f,0.f};
      int srow = st*16 + l16;
      #pragma unroll
      for (int c=0;c<6;c++){
        unsigned byte = (unsigned)(srow*384 + c*64 + g*16) ^ ((unsigned)(srow&7)<<4);
        bf16x8 kf = *reinterpret_cast<const bf16x8*>(KB + byte);
        sacc = __builtin_amdgcn_mfma_f32_16x16x32_bf16(qf[c], kf, sacc, 0, 0, 0);
      }
      S[st] = sacc;
    }
    if (sb == qt){
      #pragma unroll
      for (int st=0;st<4;st++){
        int scol = st*16 + l16;
        #pragma unroll
        for (int r=0;r<4;r++){
          int qrow = w*16 + g*4 + r;
          if (scol > qrow) S[st][r] = -1e30f;
        }
      }
    }
    float alpha[4];
    #pragma unroll
    for (int r=0;r<4;r++){
      float mx = fmaxf(fmaxf(S[0][r],S[1][r]), fmaxf(S[2][r],S[3][r]));
      #pragma unroll
      for (int off=8; off>=1; off>>=1) mx = fmaxf(mx, __shfl_xor(mx, off));
      float mnew = fmaxf(m[r], mx);
      alpha[r] = expf(m[r] - mnew);
      m[r] = mnew;
      l[r] *= alpha[r];
    }
    #pragma unroll
    for (int st=0;st<4;st++)
      #pragma unroll
      for (int r=0;r<4;r++)
        S[st][r] = expf(S[st][r] - m[r]);
    #pragma unroll
    for (int r=0;r<4;r++){
      float sum = S[0][r]+S[1][r]+S[2][r]+S[3][r];
      #pragma unroll
      for (int off=8; off>=1; off>>=1) sum += __shfl_xor(sum, off);
      l[r] += sum;
    }
    #pragma unroll
    for (int vt=0; vt<8; vt++)
      #pragma unroll
      for (int r=0;r<4;r++) o[vt][r] *= alpha[r];

    #pragma unroll
    for (int st=0;st<4;st++){
      #pragma unroll
      for (int r=0;r<4;r++){
        int qrow = g*4 + r, scol = st*16 + l16;
        unsigned byte = (unsigned)(qrow*128 + scol*2) ^ ((unsigned)(qrow&7)<<4);
        *reinterpret_cast<short*>(PB + byte) = f2bf(S[st][r]);
      }
    }
    bf16x8 pf[2];
    #pragma unroll
    for (int c=0;c<2;c++){
      unsigned byte = (unsigned)(l16*128 + (c*32 + g*8)*2) ^ ((unsigned)(l16&7)<<4);
      pf[c] = *reinterpret_cast<const bf16x8*>(PB + byte);
    }
    #pragma unroll
    for (int vt=0; vt<8; vt++){
      #pragma unroll
      for (int c=0;c<2;c++){
        int vrow = vt*16 + l16;
        unsigned byte = (unsigned)(vrow*128 + (c*32 + g*8)*2) ^ ((unsigned)(vrow&7)<<4);
        bf16x8 vf = *reinterpret_cast<const bf16x8*>(VB + byte);
        o[vt] = __builtin_amdgcn_mfma_f32_16x16x32_bf16(pf[c], vf, o[vt], 0, 0, 0);
      }
    }
  }

  #pragma unroll
  for (int r=0;r<4;r++){
    float inv = 1.f / l[r];
    int t = t0 + w*16 + g*4 + r;
    #pragma unroll
    for (int vt=0;vt<8;vt++){
      int v = vt*16 + l16;
      attn_out[(size_t)t*16384 + n*128 + v] = f2bf(o[vt][r] * inv);
    }
  }
}

// ---------------------------------------------------------------------------
extern "C" void kernel_launch(void* const* d_in, const int* in_sizes, int n_in,
                              void* d_out, int out_size, void* d_ws, size_t ws_size,
                              hipStream_t stream) {
  const float* x            = (const float*)d_in[0];
  const int*   positions    = (const int*)  d_in[1];
  const float* w_q_down     = (const float*)d_in[2];
  const float* q_norm_scale = (const float*)d_in[3];
  const float* w_q_up       = (const float*)d_in[4];
  const float* w_kv_down    = (const float*)d_in[5];
  const float* kv_norm_scale= (const float*)d_in[6];
  const float* w_kv_up      = (const float*)d_in[7];
  const float* w_o          = (const float*)d_in[8];

  char* p = (char*)d_ws;
  short* xbf   = (short*)p; p += (size_t)1024*7168*2;    // 14.7 MB
  short* wdT   = (short*)p; p += (size_t)2112*7168*2;    // 30.3 MB  [2112][7168]
  short* wquT  = (short*)p; p += (size_t)24576*1536*2;   // 75.5 MB  [24576][1536]
  short* wkuT  = (short*)p; p += (size_t)32768*512*2;    // 33.6 MB  [32768][512]
  short* woT   = (short*)p; p += (size_t)7168*16384*2;   // 234.9 MB [7168][16384]
  float* downC = (float*)p; p += (size_t)1024*2112*4;    // 8.7 MB
  short* qAbf  = (short*)p; p += (size_t)1024*1536*2;    // 3.1 MB
  short* q_b   = (short*)p; p += (size_t)1024*24576*2;   // 50.3 MB
  short* cbuf  = (short*)p; p += (size_t)1024*512*2;     // 1.0 MB
  short* krope = (short*)p; p += (size_t)1024*64*2;      // 0.13 MB
  short* kvup  = (short*)p; p += (size_t)1024*32768*2;   // 67 MB
  short* attn_o= (short*)p; p += (size_t)1024*16384*2;   // 33.6 MB

  dim3 blk(256);
  // ---- prepass: convert + transpose ----
  conv_f32_bf16<<<2048, blk, 0, stream>>>(x, xbf, 1024*7168/4);
  transpose_f32_bf16<<<dim3(24, 112),  blk, 0, stream>>>(w_q_down,  wdT,                     7168, 1536);
  transpose_f32_bf16<<<dim3(9, 112),   blk, 0, stream>>>(w_kv_down, wdT + (size_t)1536*7168, 7168, 576);
  transpose_f32_bf16<<<dim3(384, 24),  blk, 0, stream>>>(w_q_up,    wquT,                    1536, 24576);
  transpose_f32_bf16<<<dim3(512, 8),   blk, 0, stream>>>(w_kv_up,   wkuT,                    512,  32768);
  transpose_f32_bf16<<<dim3(112, 256), blk, 0, stream>>>(w_o,       woT,                     16384, 7168);

  // ---- fused down-proj: [1024][7168] @ [7168][2112] ----
  gemm_bt<float><<<dim3(8, 17), blk, 0, stream>>>(xbf, wdT, downC, 1024, 2112, 7168);
  mla_rmsnorm_bf<<<1024, blk, 0, stream>>>(downC, q_norm_scale, qAbf);
  mla_kv_post<<<1024, blk, 0, stream>>>(downC, kv_norm_scale, positions, cbuf, krope);

  // ---- up-projections ----
  gemm_bt<short><<<dim3(8, 192), blk, 0, stream>>>(qAbf, wquT, q_b, 1024, 24576, 1536);
  mla_rope_q<<<1024, blk, 0, stream>>>(q_b, positions);
  gemm_bt<short><<<dim3(8, 256), blk, 0, stream>>>(cbuf, wkuT, kvup, 1024, 32768, 512);

  // ---- attention ----
  mla_attn<<<dim3(16, 128), blk, 0, stream>>>(q_b, kvup, krope, attn_o);

  // ---- output projection ----
  gemm_bt<float><<<dim3(8, 56), blk, 0, stream>>>(attn_o, woT, (float*)d_out, 1024, 7168, 16384);
}

// Round 4
// 1245.473 us; speedup vs baseline: 3.2319x; 1.5242x over previous
//
#include <hip/hip_runtime.h>
#include <hip/hip_bf16.h>
#include <math.h>

typedef __attribute__((ext_vector_type(4))) float f32x4;
typedef __attribute__((ext_vector_type(8))) short bf16x8;
typedef __attribute__((ext_vector_type(4))) short bf16x4;

static __device__ __forceinline__ float bf2f(short u){
  unsigned int i = ((unsigned int)(unsigned short)u) << 16;
  return __builtin_bit_cast(float, i);
}
static __device__ __forceinline__ short f2bf(float f){
  unsigned int u = __builtin_bit_cast(unsigned int, f);
  u += 0x7FFFu + ((u >> 16) & 1u);   // RNE
  return (short)(u >> 16);
}

#define GLD16(g, l) __builtin_amdgcn_global_load_lds(                         \
    (const __attribute__((address_space(1))) void*)(g),                       \
    (__attribute__((address_space(3))) void*)(l), 16, 0, 0)

// ---------------------------------------------------------------------------
// C[M,N] = A[M,K] @ BT[N,K]^T.  A,BT bf16 row-major. C f32 or bf16.
// m97 structure + XCD-chunked swizzle (n-strip-major per XCD for B locality).
// Requires gridDim.x == 8 (M=1024) and (gridDim.x*gridDim.y) % 8 == 0.
// ---------------------------------------------------------------------------
template<typename CT>
__global__ __launch_bounds__(256) void gemm_bt(const short* __restrict__ A,
                                               const short* __restrict__ BT,
                                               CT* __restrict__ C,
                                               int M, int N, int K)
{
  __shared__ __align__(16) short As[128*32];
  __shared__ __align__(16) short Bs[128*32];
  const int tid = threadIdx.x;
  const int f   = blockIdx.y * gridDim.x + blockIdx.x;   // hw linear (x-major)
  const int nwg = gridDim.x * gridDim.y;
  const int cpx = nwg >> 3;
  const int t   = (f & 7) * cpx + (f >> 3);              // chunk per XCD
  const int m0  = (t & 7) * 128;                          // m-minor within chunk
  const int n0  = (t >> 3) * 128;
  const int w = tid >> 6, lane = tid & 63;
  const int wr = w >> 1, wc = w & 1;
  const int g = lane >> 4, l16 = lane & 15;

  const int sr = lane >> 2;           // row within 16-row chunk
  const int kc = (lane & 3) << 3;     // k offset (shorts)
  const int arow0 = m0 + w*16 + sr;
  const int arow1 = m0 + (w+4)*16 + sr;
  int brow0 = n0 + w*16 + sr;      if (brow0 >= N) brow0 = N - 1;
  int brow1 = n0 + (w+4)*16 + sr;  if (brow1 >= N) brow1 = N - 1;
  const short* aG0 = A  + (size_t)arow0 * K + kc;
  const short* aG1 = A  + (size_t)arow1 * K + kc;
  const short* bG0 = BT + (size_t)brow0 * K + kc;
  const short* bG1 = BT + (size_t)brow1 * K + kc;
  char* aL0 = (char*)As + (w  )*1024;
  char* aL1 = (char*)As + (w+4)*1024;
  char* bL0 = (char*)Bs + (w  )*1024;
  char* bL1 = (char*)Bs + (w+4)*1024;

  f32x4 acc[4][4];
  #pragma unroll
  for (int i=0;i<4;i++)
    #pragma unroll
    for (int j=0;j<4;j++) acc[i][j] = (f32x4){0.f,0.f,0.f,0.f};

  for (int k0 = 0; k0 < K; k0 += 32){
    __syncthreads();
    GLD16(aG0 + k0, aL0);
    GLD16(aG1 + k0, aL1);
    GLD16(bG0 + k0, bL0);
    GLD16(bG1 + k0, bL1);
    __syncthreads();

    bf16x8 af[4], bfm[4];
    #pragma unroll
    for (int mi=0;mi<4;mi++){
      int row = wr*64 + mi*16 + l16;
      af[mi] = *reinterpret_cast<const bf16x8*>((char*)As + row*64 + g*16);
    }
    #pragma unroll
    for (int ni=0;ni<4;ni++){
      int row = wc*64 + ni*16 + l16;
      bfm[ni] = *reinterpret_cast<const bf16x8*>((char*)Bs + row*64 + g*16);
    }
    #pragma unroll
    for (int mi=0;mi<4;mi++)
      #pragma unroll
      for (int ni=0;ni<4;ni++)
        acc[mi][ni] = __builtin_amdgcn_mfma_f32_16x16x32_bf16(af[mi], bfm[ni], acc[mi][ni], 0, 0, 0);
  }

  #pragma unroll
  for (int mi=0;mi<4;mi++){
    int row = m0 + wr*64 + mi*16 + g*4;
    #pragma unroll
    for (int ni=0;ni<4;ni++){
      int col = n0 + wc*64 + ni*16 + l16;
      if (col < N){
        #pragma unroll
        for (int r=0;r<4;r++){
          if constexpr (sizeof(CT) == 4)
            C[(size_t)(row+r)*N + col] = acc[mi][ni][r];
          else
            C[(size_t)(row+r)*N + col] = f2bf(acc[mi][ni][r]);
        }
      }
    }
  }
}

// ---------------------------------------------------------------------------
// dst[C][R] (bf16) = transpose(src[R][C] (f32)).  R,C multiples of 64.
// ---------------------------------------------------------------------------
__global__ __launch_bounds__(256) void transpose_f32_bf16(const float* __restrict__ src,
                                                          short* __restrict__ dst,
                                                          int R, int C)
{
  __shared__ float tl[64][68];
  const int tid = threadIdx.x;
  const int r0 = blockIdx.y * 64, c0 = blockIdx.x * 64;
  {
    const int lr = tid >> 4, lc = (tid & 15) << 2;
    #pragma unroll
    for (int p = 0; p < 4; p++){
      int row = p*16 + lr;
      f32x4 v = *reinterpret_cast<const f32x4*>(src + (size_t)(r0+row)*C + c0 + lc);
      *reinterpret_cast<f32x4*>(&tl[row][lc]) = v;
    }
  }
  __syncthreads();
  {
    const int n = tid >> 2, ks = (tid & 3) << 4;
    short tmp[16];
    #pragma unroll
    for (int j = 0; j < 16; j++) tmp[j] = f2bf(tl[ks + j][n]);
    short* d = dst + (size_t)(c0+n)*R + r0 + ks;
    *reinterpret_cast<bf16x8*>(d)     = *reinterpret_cast<bf16x8*>(&tmp[0]);
    *reinterpret_cast<bf16x8*>(d + 8) = *reinterpret_cast<bf16x8*>(&tmp[8]);
  }
}

// ---------------------------------------------------------------------------
__global__ __launch_bounds__(256) void conv_f32_bf16(const float* __restrict__ src,
                                                     short* __restrict__ dst, int n4)
{
  int i = blockIdx.x * 256 + threadIdx.x;
  const int stride = gridDim.x * 256;
  for (; i < n4; i += stride){
    f32x4 v = reinterpret_cast<const f32x4*>(src)[i];
    bf16x4 h; h[0]=f2bf(v[0]); h[1]=f2bf(v[1]); h[2]=f2bf(v[2]); h[3]=f2bf(v[3]);
    reinterpret_cast<bf16x4*>(dst)[i] = h;
  }
}

// ---------------------------------------------------------------------------
__global__ __launch_bounds__(256) void mla_rmsnorm_bf(const float* __restrict__ dc,
                                                      const float* __restrict__ scale,
                                                      short* __restrict__ out)
{
  const int t = blockIdx.x;
  const float* row = dc + (size_t)t * 2112;
  float ss = 0.f;
  for (int i = threadIdx.x; i < 1536; i += 256){ float v = row[i]; ss += v*v; }
  #pragma unroll
  for (int off = 32; off >= 1; off >>= 1) ss += __shfl_xor(ss, off);
  __shared__ float red[4];
  if ((threadIdx.x & 63) == 0) red[threadIdx.x >> 6] = ss;
  __syncthreads();
  ss = red[0] + red[1] + red[2] + red[3];
  const float rs = 1.0f / sqrtf(ss / 1536.f + 1e-6f);
  for (int i = threadIdx.x; i < 1536; i += 256)
    out[(size_t)t*1536 + i] = f2bf(row[i] * rs * scale[i]);
}

// ---------------------------------------------------------------------------
__device__ __forceinline__ void yarn_cs(int pos, int j, float& c, float& s){
  const double dim = 64.0;
  double pf = pow(10000.0, (2.0*(double)j)/dim);
  double inv_extra = 1.0/pf;
  double inv_inter = inv_extra/40.0;
  double lo = floor(dim*log(4096.0/(32.0*2.0*M_PI))/(2.0*log(10000.0)));
  double hi = ceil (dim*log(4096.0/(       2.0*M_PI))/(2.0*log(10000.0)));
  if (lo < 0.0) lo = 0.0;
  if (hi > dim - 1.0) hi = dim - 1.0;
  double denom = hi - lo; if (denom < 0.001) denom = 0.001;
  double ramp = ((double)j - lo)/denom;
  ramp = ramp < 0.0 ? 0.0 : (ramp > 1.0 ? 1.0 : ramp);
  double mask = 1.0 - ramp;
  float invf = (float)(inv_inter*(1.0 - mask) + inv_extra*mask);
  float ang = (float)pos * invf;
  c = cosf(ang); s = sinf(ang);
}

// ---------------------------------------------------------------------------
__global__ __launch_bounds__(256) void mla_rope_q(short* __restrict__ qb,
                                                  const int* __restrict__ positions)
{
  const int t = blockIdx.x;
  __shared__ float cs[32], sn[32];
  if (threadIdx.x < 32){
    float c, s; yarn_cs(positions[t], threadIdx.x, c, s);
    cs[threadIdx.x] = c; sn[threadIdx.x] = s;
  }
  __syncthreads();
  const float f = 0.004510548978043951f;   // 192^-0.5 * 256^-0.5
  short* row = qb + (size_t)t * 24576;
  for (int idx = threadIdx.x; idx < 128*160; idx += 256){
    int n = idx / 160, e = idx % 160;
    short* p = row + n*192;
    if (e < 128){
      p[e] = f2bf(bf2f(p[e]) * f);
    } else {
      int j = e - 128;
      float x1 = bf2f(p[128+j]), x2 = bf2f(p[160+j]);
      p[128+j] = f2bf((x1*cs[j] - x2*sn[j]) * f);
      p[160+j] = f2bf((x2*cs[j] + x1*sn[j]) * f);
    }
  }
}

// ---------------------------------------------------------------------------
__global__ __launch_bounds__(256) void mla_kv_post(const float* __restrict__ dc,
                                                   const float* __restrict__ scale,
                                                   const int* __restrict__ positions,
                                                   short* __restrict__ cbuf,
                                                   short* __restrict__ krope)
{
  const int t = blockIdx.x;
  const float* row = dc + (size_t)t * 2112 + 1536;
  float ss = 0.f;
  for (int i = threadIdx.x; i < 512; i += 256){ float v = row[i]; ss += v*v; }
  #pragma unroll
  for (int off = 32; off >= 1; off >>= 1) ss += __shfl_xor(ss, off);
  __shared__ float red[4];
  if ((threadIdx.x & 63) == 0) red[threadIdx.x >> 6] = ss;
  __syncthreads();
  ss = red[0] + red[1] + red[2] + red[3];
  const float rs = 1.0f / sqrtf(ss / 512.f + 1e-6f);
  for (int i = threadIdx.x; i < 512; i += 256)
    cbuf[(size_t)t*512 + i] = f2bf(row[i] * rs * scale[i]);
  if (threadIdx.x < 32){
    int j = threadIdx.x;
    float c, s; yarn_cs(positions[t], j, c, s);
    float x1 = row[512 + j], x2 = row[544 + j];
    krope[(size_t)t*64 + j]      = f2bf(x1*c - x2*s);
    krope[(size_t)t*64 + 32 + j] = f2bf(x2*c + x1*s);
  }
}

// ---------------------------------------------------------------------------
// Flash attention v2: 512 threads (8 waves x 16 q-rows = 128 q-rows/pass),
// two balanced passes (qt, 7-qt) per block -> uniform 18 iterations.
// T14 prefetch (global->reg early, LDS-write late). SBLK=64.
// XCD-chunked head mapping.  Scales pre-folded into q.
// ---------------------------------------------------------------------------
__global__ __launch_bounds__(512) void mla_attn2(const short* __restrict__ qb,
                                                 const short* __restrict__ kvup,
                                                 const short* __restrict__ krope,
                                                 short* __restrict__ attn_out)
{
  const int f = blockIdx.x;           // 0..511
  const int xcd = f & 7, pos = f >> 3;
  const int n  = xcd*16 + (pos >> 2); // head 0..127
  const int pair = pos & 3;           // q-tile pair id
  const int tid = threadIdx.x, w = tid >> 6, lane = tid & 63;
  const int g = lane >> 4, l16 = lane & 15;

  __shared__ __align__(16) short Klds[64*192];    // [s][h], XOR swizzle
  __shared__ __align__(16) short Vlds[128*64];    // V^T [v][s], rotation swizzle
  __shared__ __align__(16) short Plds[8][16*64];  // per-wave P, XOR swizzle
  char* KB = (char*)Klds; char* VB = (char*)Vlds; char* PB = (char*)Plds[w];

  bf16x8 kpre[3], vpre[2];

  // ---- staging coord precompute ----
  int kS[3], kHB[3];
  const short* kSrcBase[3];
  #pragma unroll
  for (int c=0;c<3;c++){
    int lin = c*512 + tid;
    kS[c] = lin / 24; kHB[c] = (lin % 24) * 8;
  }
  int vS[2], vVB[2], vROT[2];
  #pragma unroll
  for (int c=0;c<2;c++){
    int lin = c*512 + tid;
    vS[c] = lin >> 4; vVB[c] = (lin & 15) << 3; vROT[c] = (lin & 15) & 7;
  }

  auto stage_load = [&](int S0){
    #pragma unroll
    for (int c=0;c<3;c++){
      const short* src = (kHB[c] < 128)
        ? kvup  + (size_t)(S0 + kS[c])*32768 + n*256 + kHB[c]
        : krope + (size_t)(S0 + kS[c])*64 + (kHB[c]-128);
      kpre[c] = *reinterpret_cast<const bf16x8*>(src);
    }
    #pragma unroll
    for (int c=0;c<2;c++)
      vpre[c] = *reinterpret_cast<const bf16x8*>(kvup + (size_t)(S0 + vS[c])*32768 + n*256 + 128 + vVB[c]);
  };
  auto stage_write = [&](){
    #pragma unroll
    for (int c=0;c<3;c++){
      unsigned byte = (unsigned)(kS[c]*384 + kHB[c]*2) ^ ((unsigned)(kS[c]&7)<<4);
      *reinterpret_cast<bf16x8*>(KB + byte) = kpre[c];
    }
    #pragma unroll
    for (int c=0;c<2;c++){
      #pragma unroll
      for (int i=0;i<8;i++){
        int v = vVB[c] + i;
        unsigned byte = (unsigned)(v*128 + ((vS[c]*2 + vROT[c]*16) & 127));
        *reinterpret_cast<short*>(VB + byte) = vpre[c][i];
      }
    }
  };

  // prologue: tile (pass0, sb=0)
  stage_load(0);
  stage_write();
  __syncthreads();

  #pragma unroll
  for (int p = 0; p < 2; p++){
    const int qtl = p ? (7 - pair) : pair;
    const int t0 = qtl * 128;
    const int last = 2*qtl + 1;

    // Q fragments for this pass
    bf16x8 qf[6];
    {
      const size_t qrow = (size_t)(t0 + w*16 + l16) * 24576 + (size_t)n * 192;
      #pragma unroll
      for (int c=0;c<6;c++)
        qf[c] = *reinterpret_cast<const bf16x8*>(qb + qrow + c*32 + g*8);
    }
    f32x4 o[8];
    #pragma unroll
    for (int i=0;i<8;i++) o[i] = (f32x4){0.f,0.f,0.f,0.f};
    float m[4], l[4];
    #pragma unroll
    for (int r=0;r<4;r++){ m[r] = -1e30f; l[r] = 0.f; }

    for (int sb = 0; sb <= last; sb++){
      const bool more = (sb < last) || (p == 0);
      if (more) stage_load((sb < last) ? (sb+1)*64 : 0);

      // S = Q K^T
      f32x4 S[4];
      __builtin_amdgcn_s_setprio(1);
      #pragma unroll
      for (int st=0; st<4; st++){
        f32x4 sacc = (f32x4){0.f,0.f,0.f,0.f};
        int srow = st*16 + l16;
        #pragma unroll
        for (int c=0;c<6;c++){
          unsigned byte = (unsigned)(srow*384 + c*64 + g*16) ^ ((unsigned)(srow&7)<<4);
          bf16x8 kf = *reinterpret_cast<const bf16x8*>(KB + byte);
          sacc = __builtin_amdgcn_mfma_f32_16x16x32_bf16(qf[c], kf, sacc, 0, 0, 0);
        }
        S[st] = sacc;
      }
      __builtin_amdgcn_s_setprio(0);

      if (sb >= 2*qtl){                 // diagonal region: causal mask
        #pragma unroll
        for (int st=0;st<4;st++){
          int sg = sb*64 + st*16 + l16;
          #pragma unroll
          for (int r=0;r<4;r++){
            int qg = t0 + w*16 + g*4 + r;
            if (sg > qg) S[st][r] = -1e30f;
          }
        }
      }
      // online softmax (per 16-lane row groups)
      float alpha[4];
      #pragma unroll
      for (int r=0;r<4;r++){
        float mx = fmaxf(fmaxf(S[0][r],S[1][r]), fmaxf(S[2][r],S[3][r]));
        #pragma unroll
        for (int off=8; off>=1; off>>=1) mx = fmaxf(mx, __shfl_xor(mx, off));
        float mnew = fmaxf(m[r], mx);
        alpha[r] = __expf(m[r] - mnew);
        m[r] = mnew;
        l[r] *= alpha[r];
      }
      #pragma unroll
      for (int st=0;st<4;st++)
        #pragma unroll
        for (int r=0;r<4;r++)
          S[st][r] = __expf(S[st][r] - m[r]);
      #pragma unroll
      for (int r=0;r<4;r++){
        float sum = S[0][r]+S[1][r]+S[2][r]+S[3][r];
        #pragma unroll
        for (int off=8; off>=1; off>>=1) sum += __shfl_xor(sum, off);
        l[r] += sum;
      }
      #pragma unroll
      for (int vt=0; vt<8; vt++)
        #pragma unroll
        for (int r=0;r<4;r++) o[vt][r] *= alpha[r];

      // P -> per-wave LDS, then PV
      #pragma unroll
      for (int st=0;st<4;st++){
        #pragma unroll
        for (int r=0;r<4;r++){
          int qrow = g*4 + r, scol = st*16 + l16;
          unsigned byte = (unsigned)(qrow*128 + scol*2) ^ ((unsigned)(qrow&7)<<4);
          *reinterpret_cast<short*>(PB + byte) = f2bf(S[st][r]);
        }
      }
      bf16x8 pf[2];
      #pragma unroll
      for (int c=0;c<2;c++){
        unsigned byte = (unsigned)(l16*128 + (c*32 + g*8)*2) ^ ((unsigned)(l16&7)<<4);
        pf[c] = *reinterpret_cast<const bf16x8*>(PB + byte);
      }
      __builtin_amdgcn_s_setprio(1);
      #pragma unroll
      for (int vt=0; vt<8; vt++){
        #pragma unroll
        for (int c=0;c<2;c++){
          int vrow = vt*16 + l16;
          int rot = (vrow >> 3) & 7;
          unsigned byte = (unsigned)(vrow*128 + ((c*64 + g*16 + rot*16) & 127));
          bf16x8 vf = *reinterpret_cast<const bf16x8*>(VB + byte);
          o[vt] = __builtin_amdgcn_mfma_f32_16x16x32_bf16(pf[c], vf, o[vt], 0, 0, 0);
        }
      }
      __builtin_amdgcn_s_setprio(0);

      if (more){
        __syncthreads();     // all waves done reading K/V
        stage_write();       // prefetched regs -> LDS
        __syncthreads();     // LDS ready
      }
    }

    // epilogue for this pass
    #pragma unroll
    for (int r=0;r<4;r++){
      float inv = 1.f / l[r];
      int t = t0 + w*16 + g*4 + r;
      #pragma unroll
      for (int vt=0;vt<8;vt++){
        int v = vt*16 + l16;
        attn_out[(size_t)t*16384 + n*128 + v] = f2bf(o[vt][r] * inv);
      }
    }
  }
}

// ---------------------------------------------------------------------------
extern "C" void kernel_launch(void* const* d_in, const int* in_sizes, int n_in,
                              void* d_out, int out_size, void* d_ws, size_t ws_size,
                              hipStream_t stream) {
  const float* x            = (const float*)d_in[0];
  const int*   positions    = (const int*)  d_in[1];
  const float* w_q_down     = (const float*)d_in[2];
  const float* q_norm_scale = (const float*)d_in[3];
  const float* w_q_up       = (const float*)d_in[4];
  const float* w_kv_down    = (const float*)d_in[5];
  const float* kv_norm_scale= (const float*)d_in[6];
  const float* w_kv_up      = (const float*)d_in[7];
  const float* w_o          = (const float*)d_in[8];

  char* p = (char*)d_ws;
  short* xbf   = (short*)p; p += (size_t)1024*7168*2;    // 14.7 MB
  short* wdT   = (short*)p; p += (size_t)2112*7168*2;    // 30.3 MB  [2112][7168]
  short* wquT  = (short*)p; p += (size_t)24576*1536*2;   // 75.5 MB  [24576][1536]
  short* wkuT  = (short*)p; p += (size_t)32768*512*2;    // 33.6 MB  [32768][512]
  short* woT   = (short*)p; p += (size_t)7168*16384*2;   // 234.9 MB [7168][16384]
  float* downC = (float*)p; p += (size_t)1024*2112*4;    // 8.7 MB
  short* qAbf  = (short*)p; p += (size_t)1024*1536*2;    // 3.1 MB
  short* q_b   = (short*)p; p += (size_t)1024*24576*2;   // 50.3 MB
  short* cbuf  = (short*)p; p += (size_t)1024*512*2;     // 1.0 MB
  short* krope = (short*)p; p += (size_t)1024*64*2;      // 0.13 MB
  short* kvup  = (short*)p; p += (size_t)1024*32768*2;   // 67 MB
  short* attn_o= (short*)p; p += (size_t)1024*16384*2;   // 33.6 MB

  dim3 blk(256);
  // ---- prepass: convert + transpose ----
  conv_f32_bf16<<<2048, blk, 0, stream>>>(x, xbf, 1024*7168/4);
  transpose_f32_bf16<<<dim3(24, 112),  blk, 0, stream>>>(w_q_down,  wdT,                     7168, 1536);
  transpose_f32_bf16<<<dim3(9, 112),   blk, 0, stream>>>(w_kv_down, wdT + (size_t)1536*7168, 7168, 576);
  transpose_f32_bf16<<<dim3(384, 24),  blk, 0, stream>>>(w_q_up,    wquT,                    1536, 24576);
  transpose_f32_bf16<<<dim3(512, 8),   blk, 0, stream>>>(w_kv_up,   wkuT,                    512,  32768);
  transpose_f32_bf16<<<dim3(112, 256), blk, 0, stream>>>(w_o,       woT,                     16384, 7168);

  // ---- fused down-proj ----
  gemm_bt<float><<<dim3(8, 17), blk, 0, stream>>>(xbf, wdT, downC, 1024, 2112, 7168);
  mla_rmsnorm_bf<<<1024, blk, 0, stream>>>(downC, q_norm_scale, qAbf);
  mla_kv_post<<<1024, blk, 0, stream>>>(downC, kv_norm_scale, positions, cbuf, krope);

  // ---- up-projections ----
  gemm_bt<short><<<dim3(8, 192), blk, 0, stream>>>(qAbf, wquT, q_b, 1024, 24576, 1536);
  mla_rope_q<<<1024, blk, 0, stream>>>(q_b, positions);
  gemm_bt<short><<<dim3(8, 256), blk, 0, stream>>>(cbuf, wkuT, kvup, 1024, 32768, 512);

  // ---- attention ----
  mla_attn2<<<512, dim3(512), 0, stream>>>(q_b, kvup, krope, attn_o);

  // ---- output projection ----
  gemm_bt<float><<<dim3(8, 56), blk, 0, stream>>>(attn_o, woT, (float*)d_out, 1024, 7168, 16384);
}

// Round 5
// 1033.204 us; speedup vs baseline: 3.8959x; 1.2054x over previous
//
#include <hip/hip_runtime.h>
#include <hip/hip_bf16.h>
#include <math.h>

typedef __attribute__((ext_vector_type(4))) float f32x4;
typedef __attribute__((ext_vector_type(8))) short bf16x8;
typedef __attribute__((ext_vector_type(4))) short bf16x4;

static __device__ __forceinline__ float bf2f(short u){
  unsigned int i = ((unsigned int)(unsigned short)u) << 16;
  return __builtin_bit_cast(float, i);
}
static __device__ __forceinline__ short f2bf(float f){
  unsigned int u = __builtin_bit_cast(unsigned int, f);
  u += 0x7FFFu + ((u >> 16) & 1u);   // RNE
  return (short)(u >> 16);
}

#define GLD16(g, l) __builtin_amdgcn_global_load_lds(                         \
    (const __attribute__((address_space(1))) void*)(g),                       \
    (__attribute__((address_space(3))) void*)(l), 16, 0, 0)

// ---------------------------------------------------------------------------
// C[M,N] = A[M,K] @ BT[N,K]^T.  A,BT bf16 row-major. C f32 or bf16.
// m97 structure + XCD-chunked swizzle. SPLITS>1: K split across blockIdx.z,
// f32 partials to P[z][M][N] (reduced by reduce4 afterwards).
// Requires gridDim.x == 8 (M=1024) and (gridDim.x*gridDim.y) % 8 == 0.
// ---------------------------------------------------------------------------
template<typename CT, int SPLITS>
__global__ __launch_bounds__(256) void gemm_bt(const short* __restrict__ A,
                                               const short* __restrict__ BT,
                                               CT* __restrict__ C,
                                               float* __restrict__ P,
                                               int M, int N, int K)
{
  __shared__ __align__(16) short As[128*32];
  __shared__ __align__(16) short Bs[128*32];
  const int tid = threadIdx.x;
  const int f   = blockIdx.y * 8 + blockIdx.x;           // 2D linear (x-major)
  const int nwg = 8 * gridDim.y;
  const int cpx = nwg >> 3;
  const int t   = (f & 7) * cpx + (f >> 3);              // chunk per XCD
  const int m0  = (t & 7) * 128;                          // m-minor within chunk
  const int n0  = (t >> 3) * 128;
  const int w = tid >> 6, lane = tid & 63;
  const int wr = w >> 1, wc = w & 1;
  const int g = lane >> 4, l16 = lane & 15;

  const int Ks   = K / SPLITS;
  const int kbeg = blockIdx.z * Ks;

  const int sr = lane >> 2;           // row within 16-row chunk
  const int kc = (lane & 3) << 3;     // k offset (shorts)
  const int arow0 = m0 + w*16 + sr;
  const int arow1 = m0 + (w+4)*16 + sr;
  int brow0 = n0 + w*16 + sr;      if (brow0 >= N) brow0 = N - 1;
  int brow1 = n0 + (w+4)*16 + sr;  if (brow1 >= N) brow1 = N - 1;
  const short* aG0 = A  + (size_t)arow0 * K + kc;
  const short* aG1 = A  + (size_t)arow1 * K + kc;
  const short* bG0 = BT + (size_t)brow0 * K + kc;
  const short* bG1 = BT + (size_t)brow1 * K + kc;
  char* aL0 = (char*)As + (w  )*1024;
  char* aL1 = (char*)As + (w+4)*1024;
  char* bL0 = (char*)Bs + (w  )*1024;
  char* bL1 = (char*)Bs + (w+4)*1024;

  f32x4 acc[4][4];
  #pragma unroll
  for (int i=0;i<4;i++)
    #pragma unroll
    for (int j=0;j<4;j++) acc[i][j] = (f32x4){0.f,0.f,0.f,0.f};

  for (int k0 = kbeg; k0 < kbeg + Ks; k0 += 32){
    __syncthreads();
    GLD16(aG0 + k0, aL0);
    GLD16(aG1 + k0, aL1);
    GLD16(bG0 + k0, bL0);
    GLD16(bG1 + k0, bL1);
    __syncthreads();

    bf16x8 af[4], bfm[4];
    #pragma unroll
    for (int mi=0;mi<4;mi++){
      int row = wr*64 + mi*16 + l16;
      af[mi] = *reinterpret_cast<const bf16x8*>((char*)As + row*64 + g*16);
    }
    #pragma unroll
    for (int ni=0;ni<4;ni++){
      int row = wc*64 + ni*16 + l16;
      bfm[ni] = *reinterpret_cast<const bf16x8*>((char*)Bs + row*64 + g*16);
    }
    #pragma unroll
    for (int mi=0;mi<4;mi++)
      #pragma unroll
      for (int ni=0;ni<4;ni++)
        acc[mi][ni] = __builtin_amdgcn_mfma_f32_16x16x32_bf16(af[mi], bfm[ni], acc[mi][ni], 0, 0, 0);
  }

  // epilogue: C/D layout col=lane&15, row=(lane>>4)*4+r
  #pragma unroll
  for (int mi=0;mi<4;mi++){
    int row = m0 + wr*64 + mi*16 + g*4;
    #pragma unroll
    for (int ni=0;ni<4;ni++){
      int col = n0 + wc*64 + ni*16 + l16;
      if (col < N){
        #pragma unroll
        for (int r=0;r<4;r++){
          if constexpr (SPLITS > 1){
            P[(size_t)blockIdx.z*M*N + (size_t)(row+r)*N + col] = acc[mi][ni][r];
          } else if constexpr (sizeof(CT) == 4){
            C[(size_t)(row+r)*N + col] = acc[mi][ni][r];
          } else {
            C[(size_t)(row+r)*N + col] = f2bf(acc[mi][ni][r]);
          }
        }
      }
    }
  }
}

// ---------------------------------------------------------------------------
// out[i] = sum of 4 partial planes (fixed order -> deterministic)
// ---------------------------------------------------------------------------
__global__ __launch_bounds__(256) void reduce4(const float* __restrict__ p,
                                               float* __restrict__ out,
                                               int n4, int mn4)
{
  int i = blockIdx.x * 256 + threadIdx.x;
  const int stride = gridDim.x * 256;
  for (; i < n4; i += stride){
    f32x4 a = reinterpret_cast<const f32x4*>(p)[i];
    f32x4 b = reinterpret_cast<const f32x4*>(p)[mn4 + i];
    f32x4 c = reinterpret_cast<const f32x4*>(p)[2*mn4 + i];
    f32x4 d = reinterpret_cast<const f32x4*>(p)[3*mn4 + i];
    reinterpret_cast<f32x4*>(out)[i] = (a + b) + (c + d);
  }
}

// ---------------------------------------------------------------------------
// dst[C][R] (bf16) = transpose(src[R][C] (f32)).  R,C multiples of 64.
// ---------------------------------------------------------------------------
__global__ __launch_bounds__(256) void transpose_f32_bf16(const float* __restrict__ src,
                                                          short* __restrict__ dst,
                                                          int R, int C)
{
  __shared__ float tl[64][68];
  const int tid = threadIdx.x;
  const int r0 = blockIdx.y * 64, c0 = blockIdx.x * 64;
  {
    const int lr = tid >> 4, lc = (tid & 15) << 2;
    #pragma unroll
    for (int p = 0; p < 4; p++){
      int row = p*16 + lr;
      f32x4 v = *reinterpret_cast<const f32x4*>(src + (size_t)(r0+row)*C + c0 + lc);
      *reinterpret_cast<f32x4*>(&tl[row][lc]) = v;
    }
  }
  __syncthreads();
  {
    const int n = tid >> 2, ks = (tid & 3) << 4;
    short tmp[16];
    #pragma unroll
    for (int j = 0; j < 16; j++) tmp[j] = f2bf(tl[ks + j][n]);
    short* d = dst + (size_t)(c0+n)*R + r0 + ks;
    *reinterpret_cast<bf16x8*>(d)     = *reinterpret_cast<bf16x8*>(&tmp[0]);
    *reinterpret_cast<bf16x8*>(d + 8) = *reinterpret_cast<bf16x8*>(&tmp[8]);
  }
}

// ---------------------------------------------------------------------------
__global__ __launch_bounds__(256) void conv_f32_bf16(const float* __restrict__ src,
                                                     short* __restrict__ dst, int n4)
{
  int i = blockIdx.x * 256 + threadIdx.x;
  const int stride = gridDim.x * 256;
  for (; i < n4; i += stride){
    f32x4 v = reinterpret_cast<const f32x4*>(src)[i];
    bf16x4 h; h[0]=f2bf(v[0]); h[1]=f2bf(v[1]); h[2]=f2bf(v[2]); h[3]=f2bf(v[3]);
    reinterpret_cast<bf16x4*>(dst)[i] = h;
  }
}

// ---------------------------------------------------------------------------
__global__ __launch_bounds__(256) void mla_rmsnorm_bf(const float* __restrict__ dc,
                                                      const float* __restrict__ scale,
                                                      short* __restrict__ out)
{
  const int t = blockIdx.x;
  const float* row = dc + (size_t)t * 2112;
  float ss = 0.f;
  for (int i = threadIdx.x; i < 1536; i += 256){ float v = row[i]; ss += v*v; }
  #pragma unroll
  for (int off = 32; off >= 1; off >>= 1) ss += __shfl_xor(ss, off);
  __shared__ float red[4];
  if ((threadIdx.x & 63) == 0) red[threadIdx.x >> 6] = ss;
  __syncthreads();
  ss = red[0] + red[1] + red[2] + red[3];
  const float rs = 1.0f / sqrtf(ss / 1536.f + 1e-6f);
  for (int i = threadIdx.x; i < 1536; i += 256)
    out[(size_t)t*1536 + i] = f2bf(row[i] * rs * scale[i]);
}

// ---------------------------------------------------------------------------
__device__ __forceinline__ void yarn_cs(int pos, int j, float& c, float& s){
  const double dim = 64.0;
  double pf = pow(10000.0, (2.0*(double)j)/dim);
  double inv_extra = 1.0/pf;
  double inv_inter = inv_extra/40.0;
  double lo = floor(dim*log(4096.0/(32.0*2.0*M_PI))/(2.0*log(10000.0)));
  double hi = ceil (dim*log(4096.0/(       2.0*M_PI))/(2.0*log(10000.0)));
  if (lo < 0.0) lo = 0.0;
  if (hi > dim - 1.0) hi = dim - 1.0;
  double denom = hi - lo; if (denom < 0.001) denom = 0.001;
  double ramp = ((double)j - lo)/denom;
  ramp = ramp < 0.0 ? 0.0 : (ramp > 1.0 ? 1.0 : ramp);
  double mask = 1.0 - ramp;
  float invf = (float)(inv_inter*(1.0 - mask) + inv_extra*mask);
  float ang = (float)pos * invf;
  c = cosf(ang); s = sinf(ang);
}

// ---------------------------------------------------------------------------
__global__ __launch_bounds__(256) void mla_rope_q(short* __restrict__ qb,
                                                  const int* __restrict__ positions)
{
  const int t = blockIdx.x;
  __shared__ float cs[32], sn[32];
  if (threadIdx.x < 32){
    float c, s; yarn_cs(positions[t], threadIdx.x, c, s);
    cs[threadIdx.x] = c; sn[threadIdx.x] = s;
  }
  __syncthreads();
  const float f = 0.004510548978043951f;   // 192^-0.5 * 256^-0.5
  short* row = qb + (size_t)t * 24576;
  for (int idx = threadIdx.x; idx < 128*160; idx += 256){
    int n = idx / 160, e = idx % 160;
    short* p = row + n*192;
    if (e < 128){
      p[e] = f2bf(bf2f(p[e]) * f);
    } else {
      int j = e - 128;
      float x1 = bf2f(p[128+j]), x2 = bf2f(p[160+j]);
      p[128+j] = f2bf((x1*cs[j] - x2*sn[j]) * f);
      p[160+j] = f2bf((x2*cs[j] + x1*sn[j]) * f);
    }
  }
}

// ---------------------------------------------------------------------------
__global__ __launch_bounds__(256) void mla_kv_post(const float* __restrict__ dc,
                                                   const float* __restrict__ scale,
                                                   const int* __restrict__ positions,
                                                   short* __restrict__ cbuf,
                                                   short* __restrict__ krope)
{
  const int t = blockIdx.x;
  const float* row = dc + (size_t)t * 2112 + 1536;
  float ss = 0.f;
  for (int i = threadIdx.x; i < 512; i += 256){ float v = row[i]; ss += v*v; }
  #pragma unroll
  for (int off = 32; off >= 1; off >>= 1) ss += __shfl_xor(ss, off);
  __shared__ float red[4];
  if ((threadIdx.x & 63) == 0) red[threadIdx.x >> 6] = ss;
  __syncthreads();
  ss = red[0] + red[1] + red[2] + red[3];
  const float rs = 1.0f / sqrtf(ss / 512.f + 1e-6f);
  for (int i = threadIdx.x; i < 512; i += 256)
    cbuf[(size_t)t*512 + i] = f2bf(row[i] * rs * scale[i]);
  if (threadIdx.x < 32){
    int j = threadIdx.x;
    float c, s; yarn_cs(positions[t], j, c, s);
    float x1 = row[512 + j], x2 = row[544 + j];
    krope[(size_t)t*64 + j]      = f2bf(x1*c - x2*s);
    krope[(size_t)t*64 + 32 + j] = f2bf(x2*c + x1*s);
  }
}

// ---------------------------------------------------------------------------
// Flash attention v2: 512 threads (8 waves x 16 q-rows = 128 q-rows/pass),
// two balanced passes (qt, 7-qt) per block -> uniform 18 iterations.
// T14 prefetch (global->reg early, LDS-write late). SBLK=64.
// ---------------------------------------------------------------------------
__global__ __launch_bounds__(512) void mla_attn2(const short* __restrict__ qb,
                                                 const short* __restrict__ kvup,
                                                 const short* __restrict__ krope,
                                                 short* __restrict__ attn_out)
{
  const int f = blockIdx.x;           // 0..511
  const int xcd = f & 7, pos = f >> 3;
  const int n  = xcd*16 + (pos >> 2); // head 0..127
  const int pair = pos & 3;           // q-tile pair id
  const int tid = threadIdx.x, w = tid >> 6, lane = tid & 63;
  const int g = lane >> 4, l16 = lane & 15;

  __shared__ __align__(16) short Klds[64*192];    // [s][h], XOR swizzle
  __shared__ __align__(16) short Vlds[128*64];    // V^T [v][s], rotation swizzle
  __shared__ __align__(16) short Plds[8][16*64];  // per-wave P, XOR swizzle
  char* KB = (char*)Klds; char* VB = (char*)Vlds; char* PB = (char*)Plds[w];

  bf16x8 kpre[3], vpre[2];

  int kS[3], kHB[3];
  #pragma unroll
  for (int c=0;c<3;c++){
    int lin = c*512 + tid;
    kS[c] = lin / 24; kHB[c] = (lin % 24) * 8;
  }
  int vS[2], vVB[2], vROT[2];
  #pragma unroll
  for (int c=0;c<2;c++){
    int lin = c*512 + tid;
    vS[c] = lin >> 4; vVB[c] = (lin & 15) << 3; vROT[c] = (lin & 15) & 7;
  }

  auto stage_load = [&](int S0){
    #pragma unroll
    for (int c=0;c<3;c++){
      const short* src = (kHB[c] < 128)
        ? kvup  + (size_t)(S0 + kS[c])*32768 + n*256 + kHB[c]
        : krope + (size_t)(S0 + kS[c])*64 + (kHB[c]-128);
      kpre[c] = *reinterpret_cast<const bf16x8*>(src);
    }
    #pragma unroll
    for (int c=0;c<2;c++)
      vpre[c] = *reinterpret_cast<const bf16x8*>(kvup + (size_t)(S0 + vS[c])*32768 + n*256 + 128 + vVB[c]);
  };
  auto stage_write = [&](){
    #pragma unroll
    for (int c=0;c<3;c++){
      unsigned byte = (unsigned)(kS[c]*384 + kHB[c]*2) ^ ((unsigned)(kS[c]&7)<<4);
      *reinterpret_cast<bf16x8*>(KB + byte) = kpre[c];
    }
    #pragma unroll
    for (int c=0;c<2;c++){
      #pragma unroll
      for (int i=0;i<8;i++){
        int v = vVB[c] + i;
        unsigned byte = (unsigned)(v*128 + ((vS[c]*2 + vROT[c]*16) & 127));
        *reinterpret_cast<short*>(VB + byte) = vpre[c][i];
      }
    }
  };

  stage_load(0);
  stage_write();
  __syncthreads();

  #pragma unroll
  for (int p = 0; p < 2; p++){
    const int qtl = p ? (7 - pair) : pair;
    const int t0 = qtl * 128;
    const int last = 2*qtl + 1;

    bf16x8 qf[6];
    {
      const size_t qrow = (size_t)(t0 + w*16 + l16) * 24576 + (size_t)n * 192;
      #pragma unroll
      for (int c=0;c<6;c++)
        qf[c] = *reinterpret_cast<const bf16x8*>(qb + qrow + c*32 + g*8);
    }
    f32x4 o[8];
    #pragma unroll
    for (int i=0;i<8;i++) o[i] = (f32x4){0.f,0.f,0.f,0.f};
    float m[4], l[4];
    #pragma unroll
    for (int r=0;r<4;r++){ m[r] = -1e30f; l[r] = 0.f; }

    for (int sb = 0; sb <= last; sb++){
      const bool more = (sb < last) || (p == 0);
      if (more) stage_load((sb < last) ? (sb+1)*64 : 0);

      f32x4 S[4];
      __builtin_amdgcn_s_setprio(1);
      #pragma unroll
      for (int st=0; st<4; st++){
        f32x4 sacc = (f32x4){0.f,0.f,0.f,0.f};
        int srow = st*16 + l16;
        #pragma unroll
        for (int c=0;c<6;c++){
          unsigned byte = (unsigned)(srow*384 + c*64 + g*16) ^ ((unsigned)(srow&7)<<4);
          bf16x8 kf = *reinterpret_cast<const bf16x8*>(KB + byte);
          sacc = __builtin_amdgcn_mfma_f32_16x16x32_bf16(qf[c], kf, sacc, 0, 0, 0);
        }
        S[st] = sacc;
      }
      __builtin_amdgcn_s_setprio(0);

      if (sb >= 2*qtl){
        #pragma unroll
        for (int st=0;st<4;st++){
          int sg = sb*64 + st*16 + l16;
          #pragma unroll
          for (int r=0;r<4;r++){
            int qg = t0 + w*16 + g*4 + r;
            if (sg > qg) S[st][r] = -1e30f;
          }
        }
      }
      float alpha[4];
      #pragma unroll
      for (int r=0;r<4;r++){
        float mx = fmaxf(fmaxf(S[0][r],S[1][r]), fmaxf(S[2][r],S[3][r]));
        #pragma unroll
        for (int off=8; off>=1; off>>=1) mx = fmaxf(mx, __shfl_xor(mx, off));
        float mnew = fmaxf(m[r], mx);
        alpha[r] = __expf(m[r] - mnew);
        m[r] = mnew;
        l[r] *= alpha[r];
      }
      #pragma unroll
      for (int st=0;st<4;st++)
        #pragma unroll
        for (int r=0;r<4;r++)
          S[st][r] = __expf(S[st][r] - m[r]);
      #pragma unroll
      for (int r=0;r<4;r++){
        float sum = S[0][r]+S[1][r]+S[2][r]+S[3][r];
        #pragma unroll
        for (int off=8; off>=1; off>>=1) sum += __shfl_xor(sum, off);
        l[r] += sum;
      }
      #pragma unroll
      for (int vt=0; vt<8; vt++)
        #pragma unroll
        for (int r=0;r<4;r++) o[vt][r] *= alpha[r];

      #pragma unroll
      for (int st=0;st<4;st++){
        #pragma unroll
        for (int r=0;r<4;r++){
          int qrow = g*4 + r, scol = st*16 + l16;
          unsigned byte = (unsigned)(qrow*128 + scol*2) ^ ((unsigned)(qrow&7)<<4);
          *reinterpret_cast<short*>(PB + byte) = f2bf(S[st][r]);
        }
      }
      bf16x8 pf[2];
      #pragma unroll
      for (int c=0;c<2;c++){
        unsigned byte = (unsigned)(l16*128 + (c*32 + g*8)*2) ^ ((unsigned)(l16&7)<<4);
        pf[c] = *reinterpret_cast<const bf16x8*>(PB + byte);
      }
      __builtin_amdgcn_s_setprio(1);
      #pragma unroll
      for (int vt=0; vt<8; vt++){
        #pragma unroll
        for (int c=0;c<2;c++){
          int vrow = vt*16 + l16;
          int rot = (vrow >> 3) & 7;
          unsigned byte = (unsigned)(vrow*128 + ((c*64 + g*16 + rot*16) & 127));
          bf16x8 vf = *reinterpret_cast<const bf16x8*>(VB + byte);
          o[vt] = __builtin_amdgcn_mfma_f32_16x16x32_bf16(pf[c], vf, o[vt], 0, 0, 0);
        }
      }
      __builtin_amdgcn_s_setprio(0);

      if (more){
        __syncthreads();
        stage_write();
        __syncthreads();
      }
    }

    #pragma unroll
    for (int r=0;r<4;r++){
      float inv = 1.f / l[r];
      int t = t0 + w*16 + g*4 + r;
      #pragma unroll
      for (int vt=0;vt<8;vt++){
        int v = vt*16 + l16;
        attn_out[(size_t)t*16384 + n*128 + v] = f2bf(o[vt][r] * inv);
      }
    }
  }
}

// ---------------------------------------------------------------------------
extern "C" void kernel_launch(void* const* d_in, const int* in_sizes, int n_in,
                              void* d_out, int out_size, void* d_ws, size_t ws_size,
                              hipStream_t stream) {
  const float* x            = (const float*)d_in[0];
  const int*   positions    = (const int*)  d_in[1];
  const float* w_q_down     = (const float*)d_in[2];
  const float* q_norm_scale = (const float*)d_in[3];
  const float* w_q_up       = (const float*)d_in[4];
  const float* w_kv_down    = (const float*)d_in[5];
  const float* kv_norm_scale= (const float*)d_in[6];
  const float* w_kv_up      = (const float*)d_in[7];
  const float* w_o          = (const float*)d_in[8];

  char* p = (char*)d_ws;
  short* xbf   = (short*)p; p += (size_t)1024*7168*2;    // 14.7 MB
  short* wdT   = (short*)p; p += (size_t)2112*7168*2;    // 30.3 MB  [2112][7168]
  short* wquT  = (short*)p; p += (size_t)24576*1536*2;   // 75.5 MB  [24576][1536]
  short* wkuT  = (short*)p; p += (size_t)32768*512*2;    // 33.6 MB  [32768][512]
  short* woT   = (short*)p; p += (size_t)7168*16384*2;   // 234.9 MB [7168][16384]
  float* downC = (float*)p; p += (size_t)1024*2112*4;    // 8.7 MB
  short* qAbf  = (short*)p; p += (size_t)1024*1536*2;    // 3.1 MB
  short* q_b   = (short*)p; p += (size_t)1024*24576*2;   // 50.3 MB
  short* cbuf  = (short*)p; p += (size_t)1024*512*2;     // 1.0 MB
  short* krope = (short*)p; p += (size_t)1024*64*2;      // 0.13 MB
  short* kvup  = (short*)p; p += (size_t)1024*32768*2;   // 67 MB
  short* attn_o= (short*)p; p += (size_t)1024*16384*2;   // 33.6 MB

  // split-K partial planes (overlaying dead regions at the time of use):
  float* pDown = (float*)q_b;     // 4 x 1024 x 2112 f32 = 34.6 MB  (q_b dead until q_up GEMM)
  float* pWo   = (float*)d_ws;    // 4 x 1024 x 7168 f32 = 117.4 MB (xbf/wdT/wquT dead by then)

  dim3 blk(256);
  // ---- prepass: convert + transpose ----
  conv_f32_bf16<<<2048, blk, 0, stream>>>(x, xbf, 1024*7168/4);
  transpose_f32_bf16<<<dim3(24, 112),  blk, 0, stream>>>(w_q_down,  wdT,                     7168, 1536);
  transpose_f32_bf16<<<dim3(9, 112),   blk, 0, stream>>>(w_kv_down, wdT + (size_t)1536*7168, 7168, 576);
  transpose_f32_bf16<<<dim3(384, 24),  blk, 0, stream>>>(w_q_up,    wquT,                    1536, 24576);
  transpose_f32_bf16<<<dim3(512, 8),   blk, 0, stream>>>(w_kv_up,   wkuT,                    512,  32768);
  transpose_f32_bf16<<<dim3(112, 256), blk, 0, stream>>>(w_o,       woT,                     16384, 7168);

  // ---- fused down-proj (split-K=4: 544 blocks) ----
  gemm_bt<float, 4><<<dim3(8, 17, 4), blk, 0, stream>>>(xbf, wdT, (float*)nullptr, pDown, 1024, 2112, 7168);
  reduce4<<<1024, blk, 0, stream>>>(pDown, downC, 1024*2112/4, 1024*2112/4);
  mla_rmsnorm_bf<<<1024, blk, 0, stream>>>(downC, q_norm_scale, qAbf);
  mla_kv_post<<<1024, blk, 0, stream>>>(downC, kv_norm_scale, positions, cbuf, krope);

  // ---- up-projections ----
  gemm_bt<short, 1><<<dim3(8, 192), blk, 0, stream>>>(qAbf, wquT, q_b, nullptr, 1024, 24576, 1536);
  mla_rope_q<<<1024, blk, 0, stream>>>(q_b, positions);
  gemm_bt<short, 1><<<dim3(8, 256), blk, 0, stream>>>(cbuf, wkuT, kvup, nullptr, 1024, 32768, 512);

  // ---- attention ----
  mla_attn2<<<512, dim3(512), 0, stream>>>(q_b, kvup, krope, attn_o);

  // ---- output projection (split-K=4: 1792 blocks) ----
  gemm_bt<float, 4><<<dim3(8, 56, 4), blk, 0, stream>>>(attn_o, woT, (float*)nullptr, pWo, 1024, 7168, 16384);
  reduce4<<<2048, blk, 0, stream>>>(pWo, (float*)d_out, 1024*7168/4, 1024*7168/4);
}

// Round 6
// 974.960 us; speedup vs baseline: 4.1286x; 1.0597x over previous
//
#include <hip/hip_runtime.h>
#include <hip/hip_bf16.h>
#include <math.h>

typedef __attribute__((ext_vector_type(4))) float f32x4;
typedef __attribute__((ext_vector_type(8))) short bf16x8;
typedef __attribute__((ext_vector_type(4))) short bf16x4;

static __device__ __forceinline__ float bf2f(short u){
  unsigned int i = ((unsigned int)(unsigned short)u) << 16;
  return __builtin_bit_cast(float, i);
}
static __device__ __forceinline__ short f2bf(float f){
  unsigned int u = __builtin_bit_cast(unsigned int, f);
  u += 0x7FFFu + ((u >> 16) & 1u);   // RNE
  return (short)(u >> 16);
}

#define GLD16(g, l) __builtin_amdgcn_global_load_lds(                         \
    (const __attribute__((address_space(1))) void*)(g),                       \
    (__attribute__((address_space(3))) void*)(l), 16, 0, 0)

// ---------------------------------------------------------------------------
// C[M,N] = A[M,K] @ BT[N,K]^T.  A,BT bf16 row-major. C f32 or bf16.
// m97 structure + 2-phase double-buffered prefetch (stage t+1 before compute t)
// + XCD-chunked swizzle. SPLITS>1: K split across blockIdx.z, f32 partials.
// Requires gridDim.x == 8 (M=1024) and (gridDim.x*gridDim.y) % 8 == 0.
// ---------------------------------------------------------------------------
template<typename CT, int SPLITS>
__global__ __launch_bounds__(256) void gemm_bt(const short* __restrict__ A,
                                               const short* __restrict__ BT,
                                               CT* __restrict__ C,
                                               float* __restrict__ P,
                                               int M, int N, int K)
{
  __shared__ __align__(16) short As[2][128*32];   // 2 x 8 KB
  __shared__ __align__(16) short Bs[2][128*32];
  const int tid = threadIdx.x;
  const int f   = blockIdx.y * 8 + blockIdx.x;           // 2D linear (x-major)
  const int nwg = 8 * gridDim.y;
  const int cpx = nwg >> 3;
  const int t   = (f & 7) * cpx + (f >> 3);              // chunk per XCD
  const int m0  = (t & 7) * 128;                          // m-minor within chunk
  const int n0  = (t >> 3) * 128;
  const int w = tid >> 6, lane = tid & 63;
  const int wr = w >> 1, wc = w & 1;
  const int g = lane >> 4, l16 = lane & 15;

  const int Ks   = K / SPLITS;
  const int kbeg = blockIdx.z * Ks;
  const int kend = kbeg + Ks;

  const int sr = lane >> 2;           // row within 16-row chunk
  const int kc = (lane & 3) << 3;     // k offset (shorts)
  const int arow0 = m0 + w*16 + sr;
  const int arow1 = m0 + (w+4)*16 + sr;
  int brow0 = n0 + w*16 + sr;      if (brow0 >= N) brow0 = N - 1;
  int brow1 = n0 + (w+4)*16 + sr;  if (brow1 >= N) brow1 = N - 1;
  const short* aG0 = A  + (size_t)arow0 * K + kc;
  const short* aG1 = A  + (size_t)arow1 * K + kc;
  const short* bG0 = BT + (size_t)brow0 * K + kc;
  const short* bG1 = BT + (size_t)brow1 * K + kc;
  char* aL = (char*)As;
  char* bL = (char*)Bs;

  auto stage = [&](int buf, int k0){
    char* ab = aL + buf*8192;
    char* bb = bL + buf*8192;
    GLD16(aG0 + k0, ab + (w  )*1024);
    GLD16(aG1 + k0, ab + (w+4)*1024);
    GLD16(bG0 + k0, bb + (w  )*1024);
    GLD16(bG1 + k0, bb + (w+4)*1024);
  };

  f32x4 acc[4][4];
  #pragma unroll
  for (int i=0;i<4;i++)
    #pragma unroll
    for (int j=0;j<4;j++) acc[i][j] = (f32x4){0.f,0.f,0.f,0.f};

  // prologue: stage first tile, drain
  stage(0, kbeg);
  __syncthreads();

  int cur = 0;
  for (int k0 = kbeg; k0 < kend; k0 += 32){
    // issue next tile's loads (async into LDS) before computing current
    if (k0 + 32 < kend) stage(cur ^ 1, k0 + 32);

    const char* ar = aL + cur*8192;
    const char* br = bL + cur*8192;
    bf16x8 af[4], bfm[4];
    #pragma unroll
    for (int mi=0;mi<4;mi++){
      int row = wr*64 + mi*16 + l16;
      af[mi] = *reinterpret_cast<const bf16x8*>(ar + row*64 + g*16);
    }
    #pragma unroll
    for (int ni=0;ni<4;ni++){
      int row = wc*64 + ni*16 + l16;
      bfm[ni] = *reinterpret_cast<const bf16x8*>(br + row*64 + g*16);
    }
    #pragma unroll
    for (int mi=0;mi<4;mi++)
      #pragma unroll
      for (int ni=0;ni<4;ni++)
        acc[mi][ni] = __builtin_amdgcn_mfma_f32_16x16x32_bf16(af[mi], bfm[ni], acc[mi][ni], 0, 0, 0);

    __syncthreads();   // drains vmcnt (next tile staged) + all reads of cur done
    cur ^= 1;
  }

  // epilogue: C/D layout col=lane&15, row=(lane>>4)*4+r
  #pragma unroll
  for (int mi=0;mi<4;mi++){
    int row = m0 + wr*64 + mi*16 + g*4;
    #pragma unroll
    for (int ni=0;ni<4;ni++){
      int col = n0 + wc*64 + ni*16 + l16;
      if (col < N){
        #pragma unroll
        for (int r=0;r<4;r++){
          if constexpr (SPLITS > 1){
            P[(size_t)blockIdx.z*M*N + (size_t)(row+r)*N + col] = acc[mi][ni][r];
          } else if constexpr (sizeof(CT) == 4){
            C[(size_t)(row+r)*N + col] = acc[mi][ni][r];
          } else {
            C[(size_t)(row+r)*N + col] = f2bf(acc[mi][ni][r]);
          }
        }
      }
    }
  }
}

// ---------------------------------------------------------------------------
// out[i] = sum of NP partial planes (fixed order -> deterministic)
// ---------------------------------------------------------------------------
template<int NP>
__global__ __launch_bounds__(256) void reduceN(const float* __restrict__ p,
                                               float* __restrict__ out,
                                               int n4, int mn4)
{
  int i = blockIdx.x * 256 + threadIdx.x;
  const int stride = gridDim.x * 256;
  for (; i < n4; i += stride){
    f32x4 s = reinterpret_cast<const f32x4*>(p)[i];
    #pragma unroll
    for (int z = 1; z < NP; z++)
      s = s + reinterpret_cast<const f32x4*>(p)[(size_t)z*mn4 + i];
    reinterpret_cast<f32x4*>(out)[i] = s;
  }
}

// ---------------------------------------------------------------------------
// dst[C][R] (bf16) = transpose(src[R][C] (f32)).  R,C multiples of 64.
// ---------------------------------------------------------------------------
__global__ __launch_bounds__(256) void transpose_f32_bf16(const float* __restrict__ src,
                                                          short* __restrict__ dst,
                                                          int R, int C)
{
  __shared__ float tl[64][68];
  const int tid = threadIdx.x;
  const int r0 = blockIdx.y * 64, c0 = blockIdx.x * 64;
  {
    const int lr = tid >> 4, lc = (tid & 15) << 2;
    #pragma unroll
    for (int p = 0; p < 4; p++){
      int row = p*16 + lr;
      f32x4 v = *reinterpret_cast<const f32x4*>(src + (size_t)(r0+row)*C + c0 + lc);
      *reinterpret_cast<f32x4*>(&tl[row][lc]) = v;
    }
  }
  __syncthreads();
  {
    const int n = tid >> 2, ks = (tid & 3) << 4;
    short tmp[16];
    #pragma unroll
    for (int j = 0; j < 16; j++) tmp[j] = f2bf(tl[ks + j][n]);
    short* d = dst + (size_t)(c0+n)*R + r0 + ks;
    *reinterpret_cast<bf16x8*>(d)     = *reinterpret_cast<bf16x8*>(&tmp[0]);
    *reinterpret_cast<bf16x8*>(d + 8) = *reinterpret_cast<bf16x8*>(&tmp[8]);
  }
}

// ---------------------------------------------------------------------------
__global__ __launch_bounds__(256) void conv_f32_bf16(const float* __restrict__ src,
                                                     short* __restrict__ dst, int n4)
{
  int i = blockIdx.x * 256 + threadIdx.x;
  const int stride = gridDim.x * 256;
  for (; i < n4; i += stride){
    f32x4 v = reinterpret_cast<const f32x4*>(src)[i];
    bf16x4 h; h[0]=f2bf(v[0]); h[1]=f2bf(v[1]); h[2]=f2bf(v[2]); h[3]=f2bf(v[3]);
    reinterpret_cast<bf16x4*>(dst)[i] = h;
  }
}

// ---------------------------------------------------------------------------
__global__ __launch_bounds__(256) void mla_rmsnorm_bf(const float* __restrict__ dc,
                                                      const float* __restrict__ scale,
                                                      short* __restrict__ out)
{
  const int t = blockIdx.x;
  const float* row = dc + (size_t)t * 2112;
  float ss = 0.f;
  for (int i = threadIdx.x; i < 1536; i += 256){ float v = row[i]; ss += v*v; }
  #pragma unroll
  for (int off = 32; off >= 1; off >>= 1) ss += __shfl_xor(ss, off);
  __shared__ float red[4];
  if ((threadIdx.x & 63) == 0) red[threadIdx.x >> 6] = ss;
  __syncthreads();
  ss = red[0] + red[1] + red[2] + red[3];
  const float rs = 1.0f / sqrtf(ss / 1536.f + 1e-6f);
  for (int i = threadIdx.x; i < 1536; i += 256)
    out[(size_t)t*1536 + i] = f2bf(row[i] * rs * scale[i]);
}

// ---------------------------------------------------------------------------
__device__ __forceinline__ void yarn_cs(int pos, int j, float& c, float& s){
  const double dim = 64.0;
  double pf = pow(10000.0, (2.0*(double)j)/dim);
  double inv_extra = 1.0/pf;
  double inv_inter = inv_extra/40.0;
  double lo = floor(dim*log(4096.0/(32.0*2.0*M_PI))/(2.0*log(10000.0)));
  double hi = ceil (dim*log(4096.0/(       2.0*M_PI))/(2.0*log(10000.0)));
  if (lo < 0.0) lo = 0.0;
  if (hi > dim - 1.0) hi = dim - 1.0;
  double denom = hi - lo; if (denom < 0.001) denom = 0.001;
  double ramp = ((double)j - lo)/denom;
  ramp = ramp < 0.0 ? 0.0 : (ramp > 1.0 ? 1.0 : ramp);
  double mask = 1.0 - ramp;
  float invf = (float)(inv_inter*(1.0 - mask) + inv_extra*mask);
  float ang = (float)pos * invf;
  c = cosf(ang); s = sinf(ang);
}

// ---------------------------------------------------------------------------
__global__ __launch_bounds__(256) void mla_rope_q(short* __restrict__ qb,
                                                  const int* __restrict__ positions)
{
  const int t = blockIdx.x;
  __shared__ float cs[32], sn[32];
  if (threadIdx.x < 32){
    float c, s; yarn_cs(positions[t], threadIdx.x, c, s);
    cs[threadIdx.x] = c; sn[threadIdx.x] = s;
  }
  __syncthreads();
  const float f = 0.004510548978043951f;   // 192^-0.5 * 256^-0.5
  short* row = qb + (size_t)t * 24576;
  for (int idx = threadIdx.x; idx < 128*160; idx += 256){
    int n = idx / 160, e = idx % 160;
    short* p = row + n*192;
    if (e < 128){
      p[e] = f2bf(bf2f(p[e]) * f);
    } else {
      int j = e - 128;
      float x1 = bf2f(p[128+j]), x2 = bf2f(p[160+j]);
      p[128+j] = f2bf((x1*cs[j] - x2*sn[j]) * f);
      p[160+j] = f2bf((x2*cs[j] + x1*sn[j]) * f);
    }
  }
}

// ---------------------------------------------------------------------------
__global__ __launch_bounds__(256) void mla_kv_post(const float* __restrict__ dc,
                                                   const float* __restrict__ scale,
                                                   const int* __restrict__ positions,
                                                   short* __restrict__ cbuf,
                                                   short* __restrict__ krope)
{
  const int t = blockIdx.x;
  const float* row = dc + (size_t)t * 2112 + 1536;
  float ss = 0.f;
  for (int i = threadIdx.x; i < 512; i += 256){ float v = row[i]; ss += v*v; }
  #pragma unroll
  for (int off = 32; off >= 1; off >>= 1) ss += __shfl_xor(ss, off);
  __shared__ float red[4];
  if ((threadIdx.x & 63) == 0) red[threadIdx.x >> 6] = ss;
  __syncthreads();
  ss = red[0] + red[1] + red[2] + red[3];
  const float rs = 1.0f / sqrtf(ss / 512.f + 1e-6f);
  for (int i = threadIdx.x; i < 512; i += 256)
    cbuf[(size_t)t*512 + i] = f2bf(row[i] * rs * scale[i]);
  if (threadIdx.x < 32){
    int j = threadIdx.x;
    float c, s; yarn_cs(positions[t], j, c, s);
    float x1 = row[512 + j], x2 = row[544 + j];
    krope[(size_t)t*64 + j]      = f2bf(x1*c - x2*s);
    krope[(size_t)t*64 + 32 + j] = f2bf(x2*c + x1*s);
  }
}

// ---------------------------------------------------------------------------
// Flash attention v2: 512 threads (8 waves x 16 q-rows = 128 q-rows/pass),
// two balanced passes (qt, 7-qt) per block -> uniform 18 iterations.
// T14 prefetch (global->reg early, LDS-write late). SBLK=64.
// ---------------------------------------------------------------------------
__global__ __launch_bounds__(512) void mla_attn2(const short* __restrict__ qb,
                                                 const short* __restrict__ kvup,
                                                 const short* __restrict__ krope,
                                                 short* __restrict__ attn_out)
{
  const int f = blockIdx.x;           // 0..511
  const int xcd = f & 7, pos = f >> 3;
  const int n  = xcd*16 + (pos >> 2); // head 0..127
  const int pair = pos & 3;           // q-tile pair id
  const int tid = threadIdx.x, w = tid >> 6, lane = tid & 63;
  const int g = lane >> 4, l16 = lane & 15;

  __shared__ __align__(16) short Klds[64*192];    // [s][h], XOR swizzle
  __shared__ __align__(16) short Vlds[128*64];    // V^T [v][s], rotation swizzle
  __shared__ __align__(16) short Plds[8][16*64];  // per-wave P, XOR swizzle
  char* KB = (char*)Klds; char* VB = (char*)Vlds; char* PB = (char*)Plds[w];

  bf16x8 kpre[3], vpre[2];

  int kS[3], kHB[3];
  #pragma unroll
  for (int c=0;c<3;c++){
    int lin = c*512 + tid;
    kS[c] = lin / 24; kHB[c] = (lin % 24) * 8;
  }
  int vS[2], vVB[2], vROT[2];
  #pragma unroll
  for (int c=0;c<2;c++){
    int lin = c*512 + tid;
    vS[c] = lin >> 4; vVB[c] = (lin & 15) << 3; vROT[c] = (lin & 15) & 7;
  }

  auto stage_load = [&](int S0){
    #pragma unroll
    for (int c=0;c<3;c++){
      const short* src = (kHB[c] < 128)
        ? kvup  + (size_t)(S0 + kS[c])*32768 + n*256 + kHB[c]
        : krope + (size_t)(S0 + kS[c])*64 + (kHB[c]-128);
      kpre[c] = *reinterpret_cast<const bf16x8*>(src);
    }
    #pragma unroll
    for (int c=0;c<2;c++)
      vpre[c] = *reinterpret_cast<const bf16x8*>(kvup + (size_t)(S0 + vS[c])*32768 + n*256 + 128 + vVB[c]);
  };
  auto stage_write = [&](){
    #pragma unroll
    for (int c=0;c<3;c++){
      unsigned byte = (unsigned)(kS[c]*384 + kHB[c]*2) ^ ((unsigned)(kS[c]&7)<<4);
      *reinterpret_cast<bf16x8*>(KB + byte) = kpre[c];
    }
    #pragma unroll
    for (int c=0;c<2;c++){
      #pragma unroll
      for (int i=0;i<8;i++){
        int v = vVB[c] + i;
        unsigned byte = (unsigned)(v*128 + ((vS[c]*2 + vROT[c]*16) & 127));
        *reinterpret_cast<short*>(VB + byte) = vpre[c][i];
      }
    }
  };

  stage_load(0);
  stage_write();
  __syncthreads();

  #pragma unroll
  for (int p = 0; p < 2; p++){
    const int qtl = p ? (7 - pair) : pair;
    const int t0 = qtl * 128;
    const int last = 2*qtl + 1;

    bf16x8 qf[6];
    {
      const size_t qrow = (size_t)(t0 + w*16 + l16) * 24576 + (size_t)n * 192;
      #pragma unroll
      for (int c=0;c<6;c++)
        qf[c] = *reinterpret_cast<const bf16x8*>(qb + qrow + c*32 + g*8);
    }
    f32x4 o[8];
    #pragma unroll
    for (int i=0;i<8;i++) o[i] = (f32x4){0.f,0.f,0.f,0.f};
    float m[4], l[4];
    #pragma unroll
    for (int r=0;r<4;r++){ m[r] = -1e30f; l[r] = 0.f; }

    for (int sb = 0; sb <= last; sb++){
      const bool more = (sb < last) || (p == 0);
      if (more) stage_load((sb < last) ? (sb+1)*64 : 0);

      f32x4 S[4];
      __builtin_amdgcn_s_setprio(1);
      #pragma unroll
      for (int st=0; st<4; st++){
        f32x4 sacc = (f32x4){0.f,0.f,0.f,0.f};
        int srow = st*16 + l16;
        #pragma unroll
        for (int c=0;c<6;c++){
          unsigned byte = (unsigned)(srow*384 + c*64 + g*16) ^ ((unsigned)(srow&7)<<4);
          bf16x8 kf = *reinterpret_cast<const bf16x8*>(KB + byte);
          sacc = __builtin_amdgcn_mfma_f32_16x16x32_bf16(qf[c], kf, sacc, 0, 0, 0);
        }
        S[st] = sacc;
      }
      __builtin_amdgcn_s_setprio(0);

      if (sb >= 2*qtl){
        #pragma unroll
        for (int st=0;st<4;st++){
          int sg = sb*64 + st*16 + l16;
          #pragma unroll
          for (int r=0;r<4;r++){
            int qg = t0 + w*16 + g*4 + r;
            if (sg > qg) S[st][r] = -1e30f;
          }
        }
      }
      float alpha[4];
      #pragma unroll
      for (int r=0;r<4;r++){
        float mx = fmaxf(fmaxf(S[0][r],S[1][r]), fmaxf(S[2][r],S[3][r]));
        #pragma unroll
        for (int off=8; off>=1; off>>=1) mx = fmaxf(mx, __shfl_xor(mx, off));
        float mnew = fmaxf(m[r], mx);
        alpha[r] = __expf(m[r] - mnew);
        m[r] = mnew;
        l[r] *= alpha[r];
      }
      #pragma unroll
      for (int st=0;st<4;st++)
        #pragma unroll
        for (int r=0;r<4;r++)
          S[st][r] = __expf(S[st][r] - m[r]);
      #pragma unroll
      for (int r=0;r<4;r++){
        float sum = S[0][r]+S[1][r]+S[2][r]+S[3][r];
        #pragma unroll
        for (int off=8; off>=1; off>>=1) sum += __shfl_xor(sum, off);
        l[r] += sum;
      }
      #pragma unroll
      for (int vt=0; vt<8; vt++)
        #pragma unroll
        for (int r=0;r<4;r++) o[vt][r] *= alpha[r];

      #pragma unroll
      for (int st=0;st<4;st++){
        #pragma unroll
        for (int r=0;r<4;r++){
          int qrow = g*4 + r, scol = st*16 + l16;
          unsigned byte = (unsigned)(qrow*128 + scol*2) ^ ((unsigned)(qrow&7)<<4);
          *reinterpret_cast<short*>(PB + byte) = f2bf(S[st][r]);
        }
      }
      bf16x8 pf[2];
      #pragma unroll
      for (int c=0;c<2;c++){
        unsigned byte = (unsigned)(l16*128 + (c*32 + g*8)*2) ^ ((unsigned)(l16&7)<<4);
        pf[c] = *reinterpret_cast<const bf16x8*>(PB + byte);
      }
      __builtin_amdgcn_s_setprio(1);
      #pragma unroll
      for (int vt=0; vt<8; vt++){
        #pragma unroll
        for (int c=0;c<2;c++){
          int vrow = vt*16 + l16;
          int rot = (vrow >> 3) & 7;
          unsigned byte = (unsigned)(vrow*128 + ((c*64 + g*16 + rot*16) & 127));
          bf16x8 vf = *reinterpret_cast<const bf16x8*>(VB + byte);
          o[vt] = __builtin_amdgcn_mfma_f32_16x16x32_bf16(pf[c], vf, o[vt], 0, 0, 0);
        }
      }
      __builtin_amdgcn_s_setprio(0);

      if (more){
        __syncthreads();
        stage_write();
        __syncthreads();
      }
    }

    #pragma unroll
    for (int r=0;r<4;r++){
      float inv = 1.f / l[r];
      int t = t0 + w*16 + g*4 + r;
      #pragma unroll
      for (int vt=0;vt<8;vt++){
        int v = vt*16 + l16;
        attn_out[(size_t)t*16384 + n*128 + v] = f2bf(o[vt][r] * inv);
      }
    }
  }
}

// ---------------------------------------------------------------------------
extern "C" void kernel_launch(void* const* d_in, const int* in_sizes, int n_in,
                              void* d_out, int out_size, void* d_ws, size_t ws_size,
                              hipStream_t stream) {
  const float* x            = (const float*)d_in[0];
  const int*   positions    = (const int*)  d_in[1];
  const float* w_q_down     = (const float*)d_in[2];
  const float* q_norm_scale = (const float*)d_in[3];
  const float* w_q_up       = (const float*)d_in[4];
  const float* w_kv_down    = (const float*)d_in[5];
  const float* kv_norm_scale= (const float*)d_in[6];
  const float* w_kv_up      = (const float*)d_in[7];
  const float* w_o          = (const float*)d_in[8];

  char* p = (char*)d_ws;
  short* xbf   = (short*)p; p += (size_t)1024*7168*2;    // 14.7 MB
  short* wdT   = (short*)p; p += (size_t)2112*7168*2;    // 30.3 MB  [2112][7168]
  short* wquT  = (short*)p; p += (size_t)24576*1536*2;   // 75.5 MB  [24576][1536]
  short* wkuT  = (short*)p; p += (size_t)32768*512*2;    // 33.6 MB  [32768][512]
  short* woT   = (short*)p; p += (size_t)7168*16384*2;   // 234.9 MB [7168][16384]
  float* downC = (float*)p; p += (size_t)1024*2112*4;    // 8.7 MB
  short* qAbf  = (short*)p; p += (size_t)1024*1536*2;    // 3.1 MB
  short* q_b   = (short*)p; p += (size_t)1024*24576*2;   // 50.3 MB
  short* cbuf  = (short*)p; p += (size_t)1024*512*2;     // 1.0 MB
  short* krope = (short*)p; p += (size_t)1024*64*2;      // 0.13 MB
  short* kvup  = (short*)p; p += (size_t)1024*32768*2;   // 67 MB
  short* attn_o= (short*)p; p += (size_t)1024*16384*2;   // 33.6 MB

  // split-K partial planes (overlaying dead regions at the time of use):
  float* pDown = (float*)q_b;     // 4 x 1024 x 2112 f32 = 34.6 MB  (q_b dead until q_up GEMM)
  float* pWo   = (float*)d_ws;    // 2 x 1024 x 7168 f32 = 58.7 MB  (xbf/wdT/wquT dead by then)

  dim3 blk(256);
  // ---- prepass: convert + transpose ----
  conv_f32_bf16<<<2048, blk, 0, stream>>>(x, xbf, 1024*7168/4);
  transpose_f32_bf16<<<dim3(24, 112),  blk, 0, stream>>>(w_q_down,  wdT,                     7168, 1536);
  transpose_f32_bf16<<<dim3(9, 112),   blk, 0, stream>>>(w_kv_down, wdT + (size_t)1536*7168, 7168, 576);
  transpose_f32_bf16<<<dim3(384, 24),  blk, 0, stream>>>(w_q_up,    wquT,                    1536, 24576);
  transpose_f32_bf16<<<dim3(512, 8),   blk, 0, stream>>>(w_kv_up,   wkuT,                    512,  32768);
  transpose_f32_bf16<<<dim3(112, 256), blk, 0, stream>>>(w_o,       woT,                     16384, 7168);

  // ---- fused down-proj (split-K=4: 544 blocks) ----
  gemm_bt<float, 4><<<dim3(8, 17, 4), blk, 0, stream>>>(xbf, wdT, (float*)nullptr, pDown, 1024, 2112, 7168);
  reduceN<4><<<1024, blk, 0, stream>>>(pDown, downC, 1024*2112/4, 1024*2112/4);
  mla_rmsnorm_bf<<<1024, blk, 0, stream>>>(downC, q_norm_scale, qAbf);
  mla_kv_post<<<1024, blk, 0, stream>>>(downC, kv_norm_scale, positions, cbuf, krope);

  // ---- up-projections ----
  gemm_bt<short, 1><<<dim3(8, 192), blk, 0, stream>>>(qAbf, wquT, q_b, nullptr, 1024, 24576, 1536);
  mla_rope_q<<<1024, blk, 0, stream>>>(q_b, positions);
  gemm_bt<short, 1><<<dim3(8, 256), blk, 0, stream>>>(cbuf, wkuT, kvup, nullptr, 1024, 32768, 512);

  // ---- attention ----
  mla_attn2<<<512, dim3(512), 0, stream>>>(q_b, kvup, krope, attn_o);

  // ---- output projection (split-K=2: 896 blocks) ----
  gemm_bt<float, 2><<<dim3(8, 56, 2), blk, 0, stream>>>(attn_o, woT, (float*)nullptr, pWo, 1024, 7168, 16384);
  reduceN<2><<<2048, blk, 0, stream>>>(pWo, (float*)d_out, 1024*7168/4, 1024*7168/4);
}

// Round 8
// 883.084 us; speedup vs baseline: 4.5582x; 1.1040x over previous
//
#include <hip/hip_runtime.h>
#include <hip/hip_bf16.h>
#include <math.h>

typedef __attribute__((ext_vector_type(4))) float f32x4;
typedef __attribute__((ext_vector_type(8))) short bf16x8;
typedef __attribute__((ext_vector_type(4))) short bf16x4;

static __device__ __forceinline__ float bf2f(short u){
  unsigned int i = ((unsigned int)(unsigned short)u) << 16;
  return __builtin_bit_cast(float, i);
}
static __device__ __forceinline__ short f2bf(float f){
  unsigned int u = __builtin_bit_cast(unsigned int, f);
  u += 0x7FFFu + ((u >> 16) & 1u);   // RNE
  return (short)(u >> 16);
}

#define GLD16(g, l) __builtin_amdgcn_global_load_lds(                         \
    (const __attribute__((address_space(1))) void*)(g),                       \
    (__attribute__((address_space(3))) void*)(l), 16, 0, 0)

// ---------------------------------------------------------------------------
// gemm256: C[M,N] = A[M,K] @ BT[N,K]^T, bf16 in. 256x256 tile, BK=32, 8 waves
// (2m x 4n), per-wave 128x64. 4-slot LDS ring (128 KB dynamic), prefetch 3
// K-tiles ahead with global_load_lds; counted s_waitcnt per iter with a
// DRAIN-AWARE count (8/4/0 by tiles in flight — the round-7 race fix) + raw
// s_barrier (loads stay in flight across barriers — T4). T2 swizzle via
// pre-swizzled global source (involution, lane-constant). T5 setprio.
// ---------------------------------------------------------------------------
template<typename CT, int SPLITS>
__global__ __launch_bounds__(512, 2) void gemm256(const short* __restrict__ A,
                                                  const short* __restrict__ BT,
                                                  CT* __restrict__ C,
                                                  float* __restrict__ P,
                                                  int M, int N, int K)
{
  extern __shared__ __align__(16) char smem[];   // 4 slots x (16KB A + 16KB B)
  const int tid = threadIdx.x;
  const int w = tid >> 6, lane = tid & 63;
  const int wm = w >> 2, wn = w & 3;
  const int g = lane >> 4, l16 = lane & 15;

  // ---- XCD chunking over full linear block id (z folded in) ----
  const int per_z = gridDim.x * gridDim.y;
  const int F = (blockIdx.z * gridDim.y + blockIdx.y) * gridDim.x + blockIdx.x;
  const int nwgF = per_z * gridDim.z;
  const int cpxF = nwgF >> 3;
  const int T = (F & 7) * cpxF + (F >> 3);
  const int zz = T / per_z, tt = T % per_z;
  const int m0 = (tt & 3) * 256;          // gridDim.x == 4 (M = 1024)
  const int n0 = (tt >> 2) * 256;

  const int Ks   = K / SPLITS;
  const int kbeg = zz * Ks;
  const int NT   = Ks >> 5;               // K-tiles of 32

  // ---- staging precompute (source pre-swizzle, lane-constant) ----
  const int gg = (lane & 3) ^ ((lane >> 2) & 3) ^ ((lane >> 4) & 1);
  const short* aSrc[2]; const short* bSrc[2];
  int ldsOff[2];
  #pragma unroll
  for (int j = 0; j < 2; j++){
    int r = (w + j*8)*16 + (lane >> 2);
    aSrc[j] = A  + (size_t)(m0 + r) * K + kbeg + gg*8;
    bSrc[j] = BT + (size_t)(n0 + r) * K + kbeg + gg*8;
    ldsOff[j] = (w + j*8) * 1024;
  }

  // read-side swizzle byte offset (lane-constant)
  const int sw = ((g ^ (l16 & 3) ^ ((l16 >> 2) & 1)) << 4);

  f32x4 acc[8][4];
  #pragma unroll
  for (int i = 0; i < 8; i++)
    #pragma unroll
    for (int j = 0; j < 4; j++) acc[i][j] = (f32x4){0.f,0.f,0.f,0.f};

  auto stage = [&](int b, int t){
    const int koff = t * 32;              // shorts
    char* dst = smem + b * 32768;
    #pragma unroll
    for (int j = 0; j < 2; j++){
      GLD16(aSrc[j] + koff, dst + ldsOff[j]);
      GLD16(bSrc[j] + koff, dst + 16384 + ldsOff[j]);
    }
  };

  // drain-aware wait: ensure the NEXT tile's 4 loads (the oldest) have landed.
  auto wait_pub = [&](int ahead){       // ahead = # tiles staged beyond t
    if (ahead >= 3)      asm volatile("s_waitcnt vmcnt(8)" ::: "memory");
    else if (ahead == 2) asm volatile("s_waitcnt vmcnt(4)" ::: "memory");
    else                 asm volatile("s_waitcnt vmcnt(0)" ::: "memory");
    __builtin_amdgcn_s_barrier();
    asm volatile("" ::: "memory");
  };

  // ---- prologue: stage tiles 0..2; publish tile 0 ----
  stage(0, 0);
  if (NT > 1) stage(1, 1);
  if (NT > 2) stage(2, 2);
  wait_pub(NT - 1 >= 2 ? (NT > 2 ? 3 : 2) : 1);   // outstanding beyond tile -1

  const int arow = wm*128 + l16;          // + mi*16
  const int brow = wn*64  + l16;          // + ni*16

  for (int t = 0; t < NT; t++){
    const int sl = t & 3;
    if (t + 3 < NT) stage((t + 3) & 3, t + 3);

    const char* base = smem + sl * 32768;
    bf16x8 a[8], bb[4];
    #pragma unroll
    for (int mi = 0; mi < 8; mi++)
      a[mi] = *reinterpret_cast<const bf16x8*>(base + (arow + mi*16)*64 + sw);
    #pragma unroll
    for (int ni = 0; ni < 4; ni++)
      bb[ni] = *reinterpret_cast<const bf16x8*>(base + 16384 + (brow + ni*16)*64 + sw);

    __builtin_amdgcn_s_setprio(1);
    #pragma unroll
    for (int mi = 0; mi < 8; mi++)
      #pragma unroll
      for (int ni = 0; ni < 4; ni++)
        acc[mi][ni] = __builtin_amdgcn_mfma_f32_16x16x32_bf16(a[mi], bb[ni], acc[mi][ni], 0, 0, 0);
    __builtin_amdgcn_s_setprio(0);

    // publish tile t+1: wait own in-flight loads down to what's safe, barrier
    wait_pub(NT - 1 - t);
  }

  // ---- epilogue ----
  #pragma unroll
  for (int mi = 0; mi < 8; mi++){
    int row = m0 + wm*128 + mi*16 + g*4;
    #pragma unroll
    for (int ni = 0; ni < 4; ni++){
      int col = n0 + wn*64 + ni*16 + l16;
      #pragma unroll
      for (int r = 0; r < 4; r++){
        if constexpr (SPLITS > 1){
          P[(size_t)zz*M*N + (size_t)(row+r)*N + col] = acc[mi][ni][r];
        } else if constexpr (sizeof(CT) == 4){
          C[(size_t)(row+r)*N + col] = acc[mi][ni][r];
        } else {
          C[(size_t)(row+r)*N + col] = f2bf(acc[mi][ni][r]);
        }
      }
    }
  }
}

// ---------------------------------------------------------------------------
// Old 128x128 kernel (kept for the ragged-N down-projection, N=2112).
// ---------------------------------------------------------------------------
template<typename CT, int SPLITS>
__global__ __launch_bounds__(256) void gemm_bt(const short* __restrict__ A,
                                               const short* __restrict__ BT,
                                               CT* __restrict__ C,
                                               float* __restrict__ P,
                                               int M, int N, int K)
{
  __shared__ __align__(16) short As[2][128*32];
  __shared__ __align__(16) short Bs[2][128*32];
  const int tid = threadIdx.x;
  const int f   = blockIdx.y * 8 + blockIdx.x;
  const int nwg = 8 * gridDim.y;
  const int cpx = nwg >> 3;
  const int t   = (f & 7) * cpx + (f >> 3);
  const int m0  = (t & 7) * 128;
  const int n0  = (t >> 3) * 128;
  const int w = tid >> 6, lane = tid & 63;
  const int wr = w >> 1, wc = w & 1;
  const int g = lane >> 4, l16 = lane & 15;

  const int Ks   = K / SPLITS;
  const int kbeg = blockIdx.z * Ks;
  const int kend = kbeg + Ks;

  const int sr = lane >> 2;
  const int kc = (lane & 3) << 3;
  const int arow0 = m0 + w*16 + sr;
  const int arow1 = m0 + (w+4)*16 + sr;
  int brow0 = n0 + w*16 + sr;      if (brow0 >= N) brow0 = N - 1;
  int brow1 = n0 + (w+4)*16 + sr;  if (brow1 >= N) brow1 = N - 1;
  const short* aG0 = A  + (size_t)arow0 * K + kc;
  const short* aG1 = A  + (size_t)arow1 * K + kc;
  const short* bG0 = BT + (size_t)brow0 * K + kc;
  const short* bG1 = BT + (size_t)brow1 * K + kc;
  char* aL = (char*)As;
  char* bL = (char*)Bs;

  auto stage = [&](int buf, int k0){
    char* ab = aL + buf*8192;
    char* bb = bL + buf*8192;
    GLD16(aG0 + k0, ab + (w  )*1024);
    GLD16(aG1 + k0, ab + (w+4)*1024);
    GLD16(bG0 + k0, bb + (w  )*1024);
    GLD16(bG1 + k0, bb + (w+4)*1024);
  };

  f32x4 acc[4][4];
  #pragma unroll
  for (int i=0;i<4;i++)
    #pragma unroll
    for (int j=0;j<4;j++) acc[i][j] = (f32x4){0.f,0.f,0.f,0.f};

  stage(0, kbeg);
  __syncthreads();

  int cur = 0;
  for (int k0 = kbeg; k0 < kend; k0 += 32){
    if (k0 + 32 < kend) stage(cur ^ 1, k0 + 32);

    const char* ar = aL + cur*8192;
    const char* br = bL + cur*8192;
    bf16x8 af[4], bfm[4];
    #pragma unroll
    for (int mi=0;mi<4;mi++){
      int row = wr*64 + mi*16 + l16;
      af[mi] = *reinterpret_cast<const bf16x8*>(ar + row*64 + g*16);
    }
    #pragma unroll
    for (int ni=0;ni<4;ni++){
      int row = wc*64 + ni*16 + l16;
      bfm[ni] = *reinterpret_cast<const bf16x8*>(br + row*64 + g*16);
    }
    #pragma unroll
    for (int mi=0;mi<4;mi++)
      #pragma unroll
      for (int ni=0;ni<4;ni++)
        acc[mi][ni] = __builtin_amdgcn_mfma_f32_16x16x32_bf16(af[mi], bfm[ni], acc[mi][ni], 0, 0, 0);

    __syncthreads();
    cur ^= 1;
  }

  #pragma unroll
  for (int mi=0;mi<4;mi++){
    int row = m0 + wr*64 + mi*16 + g*4;
    #pragma unroll
    for (int ni=0;ni<4;ni++){
      int col = n0 + wc*64 + ni*16 + l16;
      if (col < N){
        #pragma unroll
        for (int r=0;r<4;r++){
          if constexpr (SPLITS > 1){
            P[(size_t)blockIdx.z*M*N + (size_t)(row+r)*N + col] = acc[mi][ni][r];
          } else if constexpr (sizeof(CT) == 4){
            C[(size_t)(row+r)*N + col] = acc[mi][ni][r];
          } else {
            C[(size_t)(row+r)*N + col] = f2bf(acc[mi][ni][r]);
          }
        }
      }
    }
  }
}

// ---------------------------------------------------------------------------
template<int NP>
__global__ __launch_bounds__(256) void reduceN(const float* __restrict__ p,
                                               float* __restrict__ out,
                                               int n4, int mn4)
{
  int i = blockIdx.x * 256 + threadIdx.x;
  const int stride = gridDim.x * 256;
  for (; i < n4; i += stride){
    f32x4 s = reinterpret_cast<const f32x4*>(p)[i];
    #pragma unroll
    for (int z = 1; z < NP; z++)
      s = s + reinterpret_cast<const f32x4*>(p)[(size_t)z*mn4 + i];
    reinterpret_cast<f32x4*>(out)[i] = s;
  }
}

// ---------------------------------------------------------------------------
__global__ __launch_bounds__(256) void transpose_f32_bf16(const float* __restrict__ src,
                                                          short* __restrict__ dst,
                                                          int R, int C)
{
  __shared__ float tl[64][68];
  const int tid = threadIdx.x;
  const int r0 = blockIdx.y * 64, c0 = blockIdx.x * 64;
  {
    const int lr = tid >> 4, lc = (tid & 15) << 2;
    #pragma unroll
    for (int p = 0; p < 4; p++){
      int row = p*16 + lr;
      f32x4 v = *reinterpret_cast<const f32x4*>(src + (size_t)(r0+row)*C + c0 + lc);
      *reinterpret_cast<f32x4*>(&tl[row][lc]) = v;
    }
  }
  __syncthreads();
  {
    const int n = tid >> 2, ks = (tid & 3) << 4;
    short tmp[16];
    #pragma unroll
    for (int j = 0; j < 16; j++) tmp[j] = f2bf(tl[ks + j][n]);
    short* d = dst + (size_t)(c0+n)*R + r0 + ks;
    *reinterpret_cast<bf16x8*>(d)     = *reinterpret_cast<bf16x8*>(&tmp[0]);
    *reinterpret_cast<bf16x8*>(d + 8) = *reinterpret_cast<bf16x8*>(&tmp[8]);
  }
}

// ---------------------------------------------------------------------------
__global__ __launch_bounds__(256) void conv_f32_bf16(const float* __restrict__ src,
                                                     short* __restrict__ dst, int n4)
{
  int i = blockIdx.x * 256 + threadIdx.x;
  const int stride = gridDim.x * 256;
  for (; i < n4; i += stride){
    f32x4 v = reinterpret_cast<const f32x4*>(src)[i];
    bf16x4 h; h[0]=f2bf(v[0]); h[1]=f2bf(v[1]); h[2]=f2bf(v[2]); h[3]=f2bf(v[3]);
    reinterpret_cast<bf16x4*>(dst)[i] = h;
  }
}

// ---------------------------------------------------------------------------
__global__ __launch_bounds__(256) void mla_rmsnorm_bf(const float* __restrict__ dc,
                                                      const float* __restrict__ scale,
                                                      short* __restrict__ out)
{
  const int t = blockIdx.x;
  const float* row = dc + (size_t)t * 2112;
  float ss = 0.f;
  for (int i = threadIdx.x; i < 1536; i += 256){ float v = row[i]; ss += v*v; }
  #pragma unroll
  for (int off = 32; off >= 1; off >>= 1) ss += __shfl_xor(ss, off);
  __shared__ float red[4];
  if ((threadIdx.x & 63) == 0) red[threadIdx.x >> 6] = ss;
  __syncthreads();
  ss = red[0] + red[1] + red[2] + red[3];
  const float rs = 1.0f / sqrtf(ss / 1536.f + 1e-6f);
  for (int i = threadIdx.x; i < 1536; i += 256)
    out[(size_t)t*1536 + i] = f2bf(row[i] * rs * scale[i]);
}

// ---------------------------------------------------------------------------
__device__ __forceinline__ void yarn_cs(int pos, int j, float& c, float& s){
  const double dim = 64.0;
  double pf = pow(10000.0, (2.0*(double)j)/dim);
  double inv_extra = 1.0/pf;
  double inv_inter = inv_extra/40.0;
  double lo = floor(dim*log(4096.0/(32.0*2.0*M_PI))/(2.0*log(10000.0)));
  double hi = ceil (dim*log(4096.0/(       2.0*M_PI))/(2.0*log(10000.0)));
  if (lo < 0.0) lo = 0.0;
  if (hi > dim - 1.0) hi = dim - 1.0;
  double denom = hi - lo; if (denom < 0.001) denom = 0.001;
  double ramp = ((double)j - lo)/denom;
  ramp = ramp < 0.0 ? 0.0 : (ramp > 1.0 ? 1.0 : ramp);
  double mask = 1.0 - ramp;
  float invf = (float)(inv_inter*(1.0 - mask) + inv_extra*mask);
  float ang = (float)pos * invf;
  c = cosf(ang); s = sinf(ang);
}

// ---------------------------------------------------------------------------
__global__ __launch_bounds__(256) void mla_rope_q(short* __restrict__ qb,
                                                  const int* __restrict__ positions)
{
  const int t = blockIdx.x;
  __shared__ float cs[32], sn[32];
  if (threadIdx.x < 32){
    float c, s; yarn_cs(positions[t], threadIdx.x, c, s);
    cs[threadIdx.x] = c; sn[threadIdx.x] = s;
  }
  __syncthreads();
  const float f = 0.004510548978043951f;   // 192^-0.5 * 256^-0.5
  short* row = qb + (size_t)t * 24576;
  for (int idx = threadIdx.x; idx < 128*160; idx += 256){
    int n = idx / 160, e = idx % 160;
    short* p = row + n*192;
    if (e < 128){
      p[e] = f2bf(bf2f(p[e]) * f);
    } else {
      int j = e - 128;
      float x1 = bf2f(p[128+j]), x2 = bf2f(p[160+j]);
      p[128+j] = f2bf((x1*cs[j] - x2*sn[j]) * f);
      p[160+j] = f2bf((x2*cs[j] + x1*sn[j]) * f);
    }
  }
}

// ---------------------------------------------------------------------------
__global__ __launch_bounds__(256) void mla_kv_post(const float* __restrict__ dc,
                                                   const float* __restrict__ scale,
                                                   const int* __restrict__ positions,
                                                   short* __restrict__ cbuf,
                                                   short* __restrict__ krope)
{
  const int t = blockIdx.x;
  const float* row = dc + (size_t)t * 2112 + 1536;
  float ss = 0.f;
  for (int i = threadIdx.x; i < 512; i += 256){ float v = row[i]; ss += v*v; }
  #pragma unroll
  for (int off = 32; off >= 1; off >>= 1) ss += __shfl_xor(ss, off);
  __shared__ float red[4];
  if ((threadIdx.x & 63) == 0) red[threadIdx.x >> 6] = ss;
  __syncthreads();
  ss = red[0] + red[1] + red[2] + red[3];
  const float rs = 1.0f / sqrtf(ss / 512.f + 1e-6f);
  for (int i = threadIdx.x; i < 512; i += 256)
    cbuf[(size_t)t*512 + i] = f2bf(row[i] * rs * scale[i]);
  if (threadIdx.x < 32){
    int j = threadIdx.x;
    float c, s; yarn_cs(positions[t], j, c, s);
    float x1 = row[512 + j], x2 = row[544 + j];
    krope[(size_t)t*64 + j]      = f2bf(x1*c - x2*s);
    krope[(size_t)t*64 + 32 + j] = f2bf(x2*c + x1*s);
  }
}

// ---------------------------------------------------------------------------
// Flash attention (unchanged; replay-stable since round 4).
// ---------------------------------------------------------------------------
__global__ __launch_bounds__(512) void mla_attn2(const short* __restrict__ qb,
                                                 const short* __restrict__ kvup,
                                                 const short* __restrict__ krope,
                                                 short* __restrict__ attn_out)
{
  const int f = blockIdx.x;
  const int xcd = f & 7, pos = f >> 3;
  const int n  = xcd*16 + (pos >> 2);
  const int pair = pos & 3;
  const int tid = threadIdx.x, w = tid >> 6, lane = tid & 63;
  const int g = lane >> 4, l16 = lane & 15;

  __shared__ __align__(16) short Klds[64*192];
  __shared__ __align__(16) short Vlds[128*64];
  __shared__ __align__(16) short Plds[8][16*64];
  char* KB = (char*)Klds; char* VB = (char*)Vlds; char* PB = (char*)Plds[w];

  bf16x8 kpre[3], vpre[2];

  int kS[3], kHB[3];
  #pragma unroll
  for (int c=0;c<3;c++){
    int lin = c*512 + tid;
    kS[c] = lin / 24; kHB[c] = (lin % 24) * 8;
  }
  int vS[2], vVB[2], vROT[2];
  #pragma unroll
  for (int c=0;c<2;c++){
    int lin = c*512 + tid;
    vS[c] = lin >> 4; vVB[c] = (lin & 15) << 3; vROT[c] = (lin & 15) & 7;
  }

  auto stage_load = [&](int S0){
    #pragma unroll
    for (int c=0;c<3;c++){
      const short* src = (kHB[c] < 128)
        ? kvup  + (size_t)(S0 + kS[c])*32768 + n*256 + kHB[c]
        : krope + (size_t)(S0 + kS[c])*64 + (kHB[c]-128);
      kpre[c] = *reinterpret_cast<const bf16x8*>(src);
    }
    #pragma unroll
    for (int c=0;c<2;c++)
      vpre[c] = *reinterpret_cast<const bf16x8*>(kvup + (size_t)(S0 + vS[c])*32768 + n*256 + 128 + vVB[c]);
  };
  auto stage_write = [&](){
    #pragma unroll
    for (int c=0;c<3;c++){
      unsigned byte = (unsigned)(kS[c]*384 + kHB[c]*2) ^ ((unsigned)(kS[c]&7)<<4);
      *reinterpret_cast<bf16x8*>(KB + byte) = kpre[c];
    }
    #pragma unroll
    for (int c=0;c<2;c++){
      #pragma unroll
      for (int i=0;i<8;i++){
        int v = vVB[c] + i;
        unsigned byte = (unsigned)(v*128 + ((vS[c]*2 + vROT[c]*16) & 127));
        *reinterpret_cast<short*>(VB + byte) = vpre[c][i];
      }
    }
  };

  stage_load(0);
  stage_write();
  __syncthreads();

  #pragma unroll
  for (int p = 0; p < 2; p++){
    const int qtl = p ? (7 - pair) : pair;
    const int t0 = qtl * 128;
    const int last = 2*qtl + 1;

    bf16x8 qf[6];
    {
      const size_t qrow = (size_t)(t0 + w*16 + l16) * 24576 + (size_t)n * 192;
      #pragma unroll
      for (int c=0;c<6;c++)
        qf[c] = *reinterpret_cast<const bf16x8*>(qb + qrow + c*32 + g*8);
    }
    f32x4 o[8];
    #pragma unroll
    for (int i=0;i<8;i++) o[i] = (f32x4){0.f,0.f,0.f,0.f};
    float m[4], l[4];
    #pragma unroll
    for (int r=0;r<4;r++){ m[r] = -1e30f; l[r] = 0.f; }

    for (int sb = 0; sb <= last; sb++){
      const bool more = (sb < last) || (p == 0);
      if (more) stage_load((sb < last) ? (sb+1)*64 : 0);

      f32x4 S[4];
      __builtin_amdgcn_s_setprio(1);
      #pragma unroll
      for (int st=0; st<4; st++){
        f32x4 sacc = (f32x4){0.f,0.f,0.f,0.f};
        int srow = st*16 + l16;
        #pragma unroll
        for (int c=0;c<6;c++){
          unsigned byte = (unsigned)(srow*384 + c*64 + g*16) ^ ((unsigned)(srow&7)<<4);
          bf16x8 kf = *reinterpret_cast<const bf16x8*>(KB + byte);
          sacc = __builtin_amdgcn_mfma_f32_16x16x32_bf16(qf[c], kf, sacc, 0, 0, 0);
        }
        S[st] = sacc;
      }
      __builtin_amdgcn_s_setprio(0);

      if (sb >= 2*qtl){
        #pragma unroll
        for (int st=0;st<4;st++){
          int sg = sb*64 + st*16 + l16;
          #pragma unroll
          for (int r=0;r<4;r++){
            int qg = t0 + w*16 + g*4 + r;
            if (sg > qg) S[st][r] = -1e30f;
          }
        }
      }
      float alpha[4];
      #pragma unroll
      for (int r=0;r<4;r++){
        float mx = fmaxf(fmaxf(S[0][r],S[1][r]), fmaxf(S[2][r],S[3][r]));
        #pragma unroll
        for (int off=8; off>=1; off>>=1) mx = fmaxf(mx, __shfl_xor(mx, off));
        float mnew = fmaxf(m[r], mx);
        alpha[r] = __expf(m[r] - mnew);
        m[r] = mnew;
        l[r] *= alpha[r];
      }
      #pragma unroll
      for (int st=0;st<4;st++)
        #pragma unroll
        for (int r=0;r<4;r++)
          S[st][r] = __expf(S[st][r] - m[r]);
      #pragma unroll
      for (int r=0;r<4;r++){
        float sum = S[0][r]+S[1][r]+S[2][r]+S[3][r];
        #pragma unroll
        for (int off=8; off>=1; off>>=1) sum += __shfl_xor(sum, off);
        l[r] += sum;
      }
      #pragma unroll
      for (int vt=0; vt<8; vt++)
        #pragma unroll
        for (int r=0;r<4;r++) o[vt][r] *= alpha[r];

      #pragma unroll
      for (int st=0;st<4;st++){
        #pragma unroll
        for (int r=0;r<4;r++){
          int qrow = g*4 + r, scol = st*16 + l16;
          unsigned byte = (unsigned)(qrow*128 + scol*2) ^ ((unsigned)(qrow&7)<<4);
          *reinterpret_cast<short*>(PB + byte) = f2bf(S[st][r]);
        }
      }
      bf16x8 pf[2];
      #pragma unroll
      for (int c=0;c<2;c++){
        unsigned byte = (unsigned)(l16*128 + (c*32 + g*8)*2) ^ ((unsigned)(l16&7)<<4);
        pf[c] = *reinterpret_cast<const bf16x8*>(PB + byte);
      }
      __builtin_amdgcn_s_setprio(1);
      #pragma unroll
      for (int vt=0; vt<8; vt++){
        #pragma unroll
        for (int c=0;c<2;c++){
          int vrow = vt*16 + l16;
          int rot = (vrow >> 3) & 7;
          unsigned byte = (unsigned)(vrow*128 + ((c*64 + g*16 + rot*16) & 127));
          bf16x8 vf = *reinterpret_cast<const bf16x8*>(VB + byte);
          o[vt] = __builtin_amdgcn_mfma_f32_16x16x32_bf16(pf[c], vf, o[vt], 0, 0, 0);
        }
      }
      __builtin_amdgcn_s_setprio(0);

      if (more){
        __syncthreads();
        stage_write();
        __syncthreads();
      }
    }

    #pragma unroll
    for (int r=0;r<4;r++){
      float inv = 1.f / l[r];
      int t = t0 + w*16 + g*4 + r;
      #pragma unroll
      for (int vt=0;vt<8;vt++){
        int v = vt*16 + l16;
        attn_out[(size_t)t*16384 + n*128 + v] = f2bf(o[vt][r] * inv);
      }
    }
  }
}

// ---------------------------------------------------------------------------
extern "C" void kernel_launch(void* const* d_in, const int* in_sizes, int n_in,
                              void* d_out, int out_size, void* d_ws, size_t ws_size,
                              hipStream_t stream) {
  const float* x            = (const float*)d_in[0];
  const int*   positions    = (const int*)  d_in[1];
  const float* w_q_down     = (const float*)d_in[2];
  const float* q_norm_scale = (const float*)d_in[3];
  const float* w_q_up       = (const float*)d_in[4];
  const float* w_kv_down    = (const float*)d_in[5];
  const float* kv_norm_scale= (const float*)d_in[6];
  const float* w_kv_up      = (const float*)d_in[7];
  const float* w_o          = (const float*)d_in[8];

  char* p = (char*)d_ws;
  short* xbf   = (short*)p; p += (size_t)1024*7168*2;    // 14.7 MB
  short* wdT   = (short*)p; p += (size_t)2112*7168*2;    // 30.3 MB  [2112][7168]
  short* wquT  = (short*)p; p += (size_t)24576*1536*2;   // 75.5 MB  [24576][1536]
  short* wkuT  = (short*)p; p += (size_t)32768*512*2;    // 33.6 MB  [32768][512]
  short* woT   = (short*)p; p += (size_t)7168*16384*2;   // 234.9 MB [7168][16384]
  float* downC = (float*)p; p += (size_t)1024*2112*4;    // 8.7 MB
  short* qAbf  = (short*)p; p += (size_t)1024*1536*2;    // 3.1 MB
  short* q_b   = (short*)p; p += (size_t)1024*24576*2;   // 50.3 MB
  short* cbuf  = (short*)p; p += (size_t)1024*512*2;     // 1.0 MB
  short* krope = (short*)p; p += (size_t)1024*64*2;      // 0.13 MB
  short* kvup  = (short*)p; p += (size_t)1024*32768*2;   // 67 MB
  short* attn_o= (short*)p; p += (size_t)1024*16384*2;   // 33.6 MB

  float* pDown = (float*)q_b;     // 4 planes of 1024x2112 f32 (q_b dead here)
  float* pWo   = (float*)d_ws;    // 2 planes of 1024x7168 f32 (prepass bufs dead)

  hipFuncSetAttribute(reinterpret_cast<const void*>(&gemm256<short,1>),
                      hipFuncAttributeMaxDynamicSharedMemorySize, 131072);
  hipFuncSetAttribute(reinterpret_cast<const void*>(&gemm256<float,2>),
                      hipFuncAttributeMaxDynamicSharedMemorySize, 131072);

  dim3 blk(256);
  // ---- prepass: convert + transpose ----
  conv_f32_bf16<<<2048, blk, 0, stream>>>(x, xbf, 1024*7168/4);
  transpose_f32_bf16<<<dim3(24, 112),  blk, 0, stream>>>(w_q_down,  wdT,                     7168, 1536);
  transpose_f32_bf16<<<dim3(9, 112),   blk, 0, stream>>>(w_kv_down, wdT + (size_t)1536*7168, 7168, 576);
  transpose_f32_bf16<<<dim3(384, 24),  blk, 0, stream>>>(w_q_up,    wquT,                    1536, 24576);
  transpose_f32_bf16<<<dim3(512, 8),   blk, 0, stream>>>(w_kv_up,   wkuT,                    512,  32768);
  transpose_f32_bf16<<<dim3(112, 256), blk, 0, stream>>>(w_o,       woT,                     16384, 7168);

  // ---- fused down-proj (old kernel, split-K=4) ----
  gemm_bt<float, 4><<<dim3(8, 17, 4), blk, 0, stream>>>(xbf, wdT, (float*)nullptr, pDown, 1024, 2112, 7168);
  reduceN<4><<<1024, blk, 0, stream>>>(pDown, downC, 1024*2112/4, 1024*2112/4);
  mla_rmsnorm_bf<<<1024, blk, 0, stream>>>(downC, q_norm_scale, qAbf);
  mla_kv_post<<<1024, blk, 0, stream>>>(downC, kv_norm_scale, positions, cbuf, krope);

  // ---- up-projections (gemm256) ----
  gemm256<short, 1><<<dim3(4, 96), dim3(512), 131072, stream>>>(qAbf, wquT, q_b, nullptr, 1024, 24576, 1536);
  mla_rope_q<<<1024, blk, 0, stream>>>(q_b, positions);
  gemm256<short, 1><<<dim3(4, 128), dim3(512), 131072, stream>>>(cbuf, wkuT, kvup, nullptr, 1024, 32768, 512);

  // ---- attention ----
  mla_attn2<<<512, dim3(512), 0, stream>>>(q_b, kvup, krope, attn_o);

  // ---- output projection (gemm256, split-K=2) ----
  gemm256<float, 2><<<dim3(4, 28, 2), dim3(512), 131072, stream>>>(attn_o, woT, (float*)nullptr, pWo, 1024, 7168, 16384);
  reduceN<2><<<2048, blk, 0, stream>>>(pWo, (float*)d_out, 1024*7168/4, 1024*7168/4);
}